// Round 14
// baseline (1838.882 us; speedup 1.0000x reference)
//
#include <hip/hip_runtime.h>
#include <hip/hip_bf16.h>
#include <stdint.h>

typedef __bf16 bf16_t;
typedef __bf16 bf16x8 __attribute__((ext_vector_type(8)));
typedef __bf16 bf16x4 __attribute__((ext_vector_type(4)));
typedef float f32x4 __attribute__((ext_vector_type(4)));

// Problem constants: B=32, H=W=64, C=256, heads=8, ws=8, ss=4
#define MROWS 131072   // B * 64 * 64 tokens (window layout rows)

__device__ __forceinline__ bf16_t to_bf16(float f) {
  __hip_bfloat16 h = __float2bfloat16(f);   // RNE
  return *reinterpret_cast<bf16_t*>(&h);
}

__device__ __forceinline__ f32x4 mfma16(bf16x8 a, bf16x8 b, f32x4 c) {
  return __builtin_amdgcn_mfma_f32_16x16x32_bf16(a, b, c, 0, 0, 0);
}

__device__ __forceinline__ void gload16(const void* g, void* l) {
  __builtin_amdgcn_global_load_lds(
      (const __attribute__((address_space(1))) void*)g,
      (__attribute__((address_space(3))) void*)l, 16, 0, 0);
}

// window-layout row m  ->  x row (shift+partition gather; reverse+unshift scatter)
__device__ __forceinline__ int map_row(int m) {
  int b   = m >> 12;
  int rem = m & 4095;
  int win = rem >> 6;
  int n   = rem & 63;
  int gh  = ((win >> 3) << 3) + (n >> 3);
  int gw  = ((win & 7) << 3) + (n & 7);
  int sh  = (gh + 4) & 63;
  int sw  = (gw + 4) & 63;
  return (b << 12) + (sh << 6) + sw;
}

// ---------------- fp32 -> bf16 weight convert (all 4 weight mats, one launch) ------
__global__ __launch_bounds__(256) void cvt_all(const float* __restrict__ qkv_w,
                                               const float* __restrict__ proj_w,
                                               const float* __restrict__ fc1_w,
                                               const float* __restrict__ fc2_w,
                                               bf16_t* __restrict__ qkv_o,
                                               bf16_t* __restrict__ proj_o,
                                               bf16_t* __restrict__ fc1_o,
                                               bf16_t* __restrict__ fc2_o) {
  int i = blockIdx.x * 256 + threadIdx.x;   // 0 .. 786431
  if (i < 196608)       qkv_o[i] = to_bf16(qkv_w[i]);
  else if (i < 262144)  proj_o[i - 196608] = to_bf16(proj_w[i - 196608]);
  else if (i < 524288)  fc1_o[i - 262144] = to_bf16(fc1_w[i - 262144]);
  else                  fc2_o[i - 524288] = to_bf16(fc2_w[i - 524288]);
}

// ---------------- bias table: bias[cls][h][n][m] = rpb(n,m,h) + mask(cls,n,m) ------
__global__ __launch_bounds__(256) void bias_kernel(const float* __restrict__ rpbt,
                                                   float* __restrict__ bias) {
  int idx = blockIdx.x * 256 + threadIdx.x;   // 0 .. 131071
  int m = idx & 63, n = (idx >> 6) & 63, h = (idx >> 12) & 7, c = idx >> 15;
  int yn = n >> 3, xn = n & 7, ym = m >> 3, xm = m & 7;
  float v = rpbt[((yn - ym + 7) * 15 + (xn - xm + 7)) * 8 + h];
  int rn = (c & 2) ? (yn < 4 ? 1 : 2) : 0;
  int cn = (c & 1) ? (xn < 4 ? 1 : 2) : 0;
  int rm = (c & 2) ? (ym < 4 ? 1 : 2) : 0;
  int cm = (c & 1) ? (xm < 4 ? 1 : 2) : 0;
  if (rn * 3 + cn != rm * 3 + cm) v -= 100.0f;
  bias[idx] = v;
}

// ---------------- LayerNorm (wave per row), row-permuted gather (LN1) ----------------
template <bool PERM>
__global__ __launch_bounds__(256) void ln_kernel(const float* __restrict__ xin,
                                                 const float* __restrict__ g,
                                                 const float* __restrict__ b,
                                                 bf16_t* __restrict__ out) {
  int row  = (blockIdx.x << 2) + (threadIdx.x >> 6);
  int lane = threadIdx.x & 63;
  int src  = PERM ? map_row(row) : row;
  float4 v = *reinterpret_cast<const float4*>(xin + (size_t)src * 256 + (lane << 2));
  float s = v.x + v.y + v.z + v.w;
#pragma unroll
  for (int d = 1; d < 64; d <<= 1) s += __shfl_xor(s, d);
  float mean = s * 0.00390625f;
  float ax = v.x - mean, ay = v.y - mean, az = v.z - mean, aw = v.w - mean;
  float s2 = ax * ax + ay * ay + az * az + aw * aw;
#pragma unroll
  for (int d = 1; d < 64; d <<= 1) s2 += __shfl_xor(s2, d);
  float rstd = rsqrtf(s2 * 0.00390625f + 1e-5f);
  float4 gv = *reinterpret_cast<const float4*>(g + (lane << 2));
  float4 bv = *reinterpret_cast<const float4*>(b + (lane << 2));
  bf16x4 o4;
  o4[0] = to_bf16(ax * rstd * gv.x + bv.x);
  o4[1] = to_bf16(ay * rstd * gv.y + bv.y);
  o4[2] = to_bf16(az * rstd * gv.z + bv.z);
  o4[3] = to_bf16(aw * rstd * gv.w + bv.w);
  *reinterpret_cast<bf16x4*>(out + (size_t)row * 256 + (lane << 2)) = o4;
}

// ======== 128(M)x256(N)-tile, 8 waves (2Mx4N), BK=32 ========
// v3: DOUBLE-buffered LDS (48KB) + depth-2 cross-barrier staging:
//   compute(t) -> s_barrier (buf dead) -> STG(t+2 into freed buf) -> vmcnt(3)
//   (retires t+1; t+2 flies across the barrier) -> s_barrier.
// 3 blocks/CU (24 waves, launch_bounds(512,6)). T2 swizzle both-sides; T1; T5.
// EPI 1: GELU -> bf16 via two-pass LDS-bounce (h2)
// EPI 2: proj: fp32 permuted store + resid + FUSED LN2 -> x2n
// EPI 4: qkv head-major split via two-pass LDS-bounce
template <int EPI>
__global__ __launch_bounds__(512, 6) void gemm128x256(const bf16_t* __restrict__ A,
                                                      const bf16_t* __restrict__ W,
                                                      const float* __restrict__ bias,
                                                      void* __restrict__ outp,
                                                      void* __restrict__ outp2,
                                                      void* __restrict__ outp3,
                                                      const float* __restrict__ resid,
                                                      const float* __restrict__ n2g,
                                                      const float* __restrict__ n2b,
                                                      bf16_t* __restrict__ x2n,
                                                      int M, int N, int K, int NBN) {
  extern __shared__ __align__(16) char smem[];
  bf16_t* As  = (bf16_t*)smem;              // [2][128*32]  (16 KB)
  bf16_t* Bs  = As + 2 * 4096;              // [2][256*32]  (32 KB)
  float*  lnS = (float*)(Bs + 2 * 8192);    // EPI2: [128][4]
  float*  lnQ = lnS + 512;                  // [128][4]
  float*  lnMR = lnQ + 512;                 // [128][2]
  const int tid  = threadIdx.x;
  const int lane = tid & 63, lo = lane & 15, hi = lane >> 4;
  const int wid  = tid >> 6, wm = wid >> 2, wn = wid & 3;
  const int cpx = gridDim.x >> 3;           // T1 XCD chunk swizzle
  const int wg  = (blockIdx.x & 7) * cpx + (blockIdx.x >> 3);
  const int bn = (wg % NBN) << 8, bm = (wg / NBN) << 7;
  f32x4 acc[4][4] = {};

  // STAGE one K-tile: 3 gloads/thread (A:1, B:2); source 16B-slot pre-swizzled (T2)
#define STG(buf, kt)                                                          \
  {                                                                           \
    int k0s = (kt) << 5;                                                      \
    {                                                                         \
      int ch = tid;                                                           \
      int row = ch >> 2, sl = ((ch & 3) ^ ((row >> 1) & 3)) << 3;             \
      gload16(A + (size_t)(bm + row) * K + k0s + sl,                          \
              &As[((buf) << 12) + (ch << 3)]);                                \
    }                                                                         \
    _Pragma("unroll") for (int l = 0; l < 2; ++l) {                           \
      int ch = (l << 9) + tid;                                                \
      int row = ch >> 2, sl = ((ch & 3) ^ ((row >> 1) & 3)) << 3;             \
      gload16(W + (size_t)(bn + row) * K + k0s + sl,                          \
              &Bs[((buf) << 13) + (ch << 3)]);                                \
    }                                                                         \
  }

  const int nt = K >> 5;                    // 8 (K=256)
  STG(0, 0);
  STG(1, 1);                                // 6 loads/thread outstanding
  asm volatile("s_waitcnt vmcnt(3)" ::: "memory");   // tile 0 landed (tile 1 flying)
  __builtin_amdgcn_s_barrier();

  for (int t = 0; t < nt; ++t) {
    const int cur = t & 1;
    const bf16_t* as = &As[cur << 12];
    const bf16_t* bs = &Bs[cur << 13];
    bf16x8 af[4], bfr[4];
#pragma unroll
    for (int i = 0; i < 4; ++i) {
      int ra = (wm << 6) + (i << 4) + lo;
      af[i] = *reinterpret_cast<const bf16x8*>(&as[ra * 32 + ((hi ^ ((ra >> 1) & 3)) << 3)]);
    }
#pragma unroll
    for (int j = 0; j < 4; ++j) {
      int rb = (wn << 6) + (j << 4) + lo;
      bfr[j] = *reinterpret_cast<const bf16x8*>(&bs[rb * 32 + ((hi ^ ((rb >> 1) & 3)) << 3)]);
    }
    __builtin_amdgcn_s_setprio(1);          // T5
#pragma unroll
    for (int i = 0; i < 4; ++i)
#pragma unroll
      for (int j = 0; j < 4; ++j)
        acc[i][j] = mfma16(af[i], bfr[j], acc[i][j]);
    __builtin_amdgcn_s_setprio(0);
    if (t + 1 < nt) {
      __builtin_amdgcn_s_barrier();         // all waves done reading buf cur
      if (t + 2 < nt) {
        STG(cur, t + 2);                    // refill freed buf; flies across barrier
        asm volatile("s_waitcnt vmcnt(3)" ::: "memory");   // t+1 retired
      } else {
        asm volatile("s_waitcnt vmcnt(0)" ::: "memory");
      }
      __builtin_amdgcn_s_barrier();         // tile t+1 visible everywhere
    }
  }
#undef STG

  float bv4[4];
#pragma unroll
  for (int nf = 0; nf < 4; ++nf) bv4[nf] = bias[bn + (wn << 6) + (nf << 4) + lo];

  if constexpr (EPI == 2) {
    // proj epilogue (BN = N = 256: full rows in-block): x2 = resid + o + b -> out
    // (permuted rows, fp32), then fused LN2 -> x2n bf16.
    float* o = (float*)outp;
    float gv[4], bnv[4];
#pragma unroll
    for (int nf = 0; nf < 4; ++nf) {
      int col = (wn << 6) + (nf << 4) + lo;
      gv[nf] = n2g[col]; bnv[nf] = n2b[col];
    }
#pragma unroll
    for (int mf = 0; mf < 4; ++mf)
#pragma unroll
      for (int r = 0; r < 4; ++r) {
        int rl = (wm << 6) + (mf << 4) + (hi << 2) + r;   // 0..127
        int xr = map_row(bm + rl);
        float s = 0.f, q = 0.f;
#pragma unroll
        for (int nf = 0; nf < 4; ++nf) {
          int col = (wn << 6) + (nf << 4) + lo;
          size_t idx = (size_t)xr * 256 + col;
          float v = resid[idx] + acc[mf][nf][r] + bv4[nf];
          acc[mf][nf][r] = v;
          o[idx] = v;
          s += v; q += v * v;
        }
#pragma unroll
        for (int d = 1; d < 16; d <<= 1) { s += __shfl_xor(s, d); q += __shfl_xor(q, d); }
        if (lo == 0) { lnS[(rl << 2) + wn] = s; lnQ[(rl << 2) + wn] = q; }
      }
    __syncthreads();
    if (tid < 128) {
      float s = lnS[tid << 2] + lnS[(tid << 2) + 1] + lnS[(tid << 2) + 2] + lnS[(tid << 2) + 3];
      float q = lnQ[tid << 2] + lnQ[(tid << 2) + 1] + lnQ[(tid << 2) + 2] + lnQ[(tid << 2) + 3];
      float mean = s * 0.00390625f;
      float var  = q * 0.00390625f - mean * mean;
      lnMR[tid << 1] = mean;
      lnMR[(tid << 1) + 1] = rsqrtf(var + 1e-5f);
    }
    __syncthreads();
#pragma unroll
    for (int mf = 0; mf < 4; ++mf)
#pragma unroll
      for (int r = 0; r < 4; ++r) {
        int rl = (wm << 6) + (mf << 4) + (hi << 2) + r;
        int xr = map_row(bm + rl);
        float mean = lnMR[rl << 1], rstd = lnMR[(rl << 1) + 1];
#pragma unroll
        for (int nf = 0; nf < 4; ++nf) {
          int col = (wn << 6) + (nf << 4) + lo;
          x2n[(size_t)xr * 256 + col] = to_bf16((acc[mf][nf][r] - mean) * rstd * gv[nf] + bnv[nf]);
        }
      }
  } else if constexpr (EPI == 4) {
    // QKV: two-pass LDS-bounce (Os[64][264] fits the 48KB buffers); wave wid
    // streams head wid's contiguous 4KB run per pass.
    bf16_t* base = (bn == 0) ? (bf16_t*)outp
                 : (bn == 256) ? (bf16_t*)outp2 : (bf16_t*)outp3;
    bf16_t* Os = (bf16_t*)smem;             // [64][264] = 33.8 KB
#pragma unroll
    for (int pass = 0; pass < 2; ++pass) {
      __syncthreads();                      // buffers dead / prev pass streamed
      if (wm == pass) {
#pragma unroll
        for (int mf = 0; mf < 4; ++mf)
#pragma unroll
          for (int r = 0; r < 4; ++r) {
            int rl = (mf << 4) + (hi << 2) + r;   // local 0..63
#pragma unroll
            for (int nf = 0; nf < 4; ++nf) {
              int col = (wn << 6) + (nf << 4) + lo;
              Os[rl * 264 + col] = to_bf16(acc[mf][nf][r] + bv4[nf]);
            }
          }
      }
      __syncthreads();
      bf16_t* dst = base + ((size_t)wid * MROWS + bm + (pass << 6)) * 32;
#pragma unroll
      for (int p = 0; p < 4; ++p) {
        int off = (p << 9) + (lane << 3);   // 0..2047 el (64 rows x 32)
        int row = off >> 5, d0 = off & 31;
        bf16x8 vv = *reinterpret_cast<const bf16x8*>(&Os[row * 264 + (wid << 5) + d0]);
        *reinterpret_cast<bf16x8*>(dst + off) = vv;
      }
    }
  } else {
    // EPI 1: GELU -> bf16 via two-pass LDS-bounce, coalesced row-major store (h2)
    bf16_t* o = (bf16_t*)outp;
    bf16_t* Os = (bf16_t*)smem;             // [64][264]
#pragma unroll
    for (int pass = 0; pass < 2; ++pass) {
      __syncthreads();
      if (wm == pass) {
#pragma unroll
        for (int mf = 0; mf < 4; ++mf)
#pragma unroll
          for (int r = 0; r < 4; ++r) {
            int rl = (mf << 4) + (hi << 2) + r;   // local 0..63
#pragma unroll
            for (int nf = 0; nf < 4; ++nf) {
              int col = (wn << 6) + (nf << 4) + lo;
              float v = acc[mf][nf][r] + bv4[nf];
              if constexpr (EPI == 1) v = 0.5f * v * (1.0f + erff(v * 0.70710678118654752f));
              Os[rl * 264 + col] = to_bf16(v);
            }
          }
      }
      __syncthreads();
#pragma unroll
      for (int p = 0; p < 4; ++p) {
        int off = (p << 9) + (lane << 3);   // wave's 8 rows x 256 cols
        int row = (wid << 3) + (off >> 8);  // 0..63
        int col = off & 255;
        bf16x8 vv = *reinterpret_cast<const bf16x8*>(&Os[row * 264 + col]);
        *reinterpret_cast<bf16x8*>(o + (size_t)(bm + (pass << 6) + row) * N + bn + col) = vv;
      }
    }
  }
}

// ---------------- 128x128 bf16 GEMM, 3-stage counted-vmcnt (r8 proven) — FC2 ------
template <int EPI>
__global__ __launch_bounds__(256) void gemm_bt(const bf16_t* __restrict__ A,
                                               const bf16_t* __restrict__ W,
                                               const float* __restrict__ bias,
                                               void* __restrict__ outp,
                                               int M, int N, int K, int NBN) {
  __shared__ __align__(16) bf16_t As[3 * 128 * 32];
  __shared__ __align__(16) bf16_t Bs[3 * 128 * 32];
  const int tid  = threadIdx.x;
  const int lane = tid & 63, lo = lane & 15, hi = lane >> 4;
  const int wave = tid >> 6;
  const int cpx = gridDim.x >> 3;
  const int wg  = (blockIdx.x & 7) * cpx + (blockIdx.x >> 3);
  const int bn = (wg % NBN) << 7, bm = (wg / NBN) << 7;
  const int wr = (wave >> 1) << 6, wc = (wave & 1) << 6;
  f32x4 acc[4][4] = {};

#define STAGE(buf, kt)                                                         \
  {                                                                            \
    int k0s = (kt) << 5;                                                       \
    _Pragma("unroll") for (int it = 0; it < 2; ++it) {                         \
      int ch = (it << 8) + tid;                                                \
      int r = ch >> 2;                                                         \
      int kf = ((ch & 3) ^ ((r >> 1) & 3)) << 3;                               \
      gload16(A + (size_t)(bm + r) * K + k0s + kf, &As[((buf) << 12) + (ch << 3)]); \
      gload16(W + (size_t)(bn + r) * K + k0s + kf, &Bs[((buf) << 12) + (ch << 3)]); \
    }                                                                          \
  }

  const int nt = K >> 5;
  STAGE(0, 0);
  STAGE(1, 1);

  int cb = 0;
  for (int t = 0; t < nt; ++t) {
    if (t + 1 < nt) { asm volatile("s_waitcnt vmcnt(4)" ::: "memory"); }
    else            { asm volatile("s_waitcnt vmcnt(0)" ::: "memory"); }
    __builtin_amdgcn_s_barrier();
    if (t + 2 < nt) {
      int sb = (cb == 0) ? 2 : cb - 1;
      STAGE(sb, t + 2);
    }
    const bf16_t* as = &As[cb << 12];
    const bf16_t* bs = &Bs[cb << 12];
    bf16x8 af[4], bfr[4];
#pragma unroll
    for (int i = 0; i < 4; ++i) {
      int ra = wr + (i << 4) + lo;
      af[i] = *reinterpret_cast<const bf16x8*>(&as[ra * 32 + ((hi ^ ((ra >> 1) & 3)) << 3)]);
    }
#pragma unroll
    for (int j = 0; j < 4; ++j) {
      int rb = wc + (j << 4) + lo;
      bfr[j] = *reinterpret_cast<const bf16x8*>(&bs[rb * 32 + ((hi ^ ((rb >> 1) & 3)) << 3)]);
    }
    __builtin_amdgcn_s_setprio(1);
#pragma unroll
    for (int i = 0; i < 4; ++i)
#pragma unroll
      for (int j = 0; j < 4; ++j)
        acc[i][j] = mfma16(af[i], bfr[j], acc[i][j]);
    __builtin_amdgcn_s_setprio(0);
    cb = (cb == 2) ? 0 : cb + 1;
  }
#undef STAGE

  float bv[4];
#pragma unroll
  for (int j = 0; j < 4; ++j) bv[j] = bias[bn + wc + (j << 4) + lo];

#pragma unroll
  for (int i = 0; i < 4; ++i)
#pragma unroll
    for (int r = 0; r < 4; ++r) {
      int row = bm + wr + (i << 4) + (hi << 2) + r;
      float* o = (float*)outp;   // EPI 3 only
#pragma unroll
      for (int j = 0; j < 4; ++j) {
        int col = bn + wc + (j << 4) + lo;
        size_t idx = (size_t)row * 256 + col;
        o[idx] = o[idx] + acc[i][j][r] + bv[j];
      }
    }
}

// ---------------- windowed attention v2: wave PAIR per (window, head) ----------------
// Pl stride 68 (softmax writes stay conflict-free; PV pa-reads ~4-way, cheap)
// -> static LDS 53,248 B -> 3 blocks/CU (24 waves with launch_bounds(512,6)).
__global__ __launch_bounds__(512, 6) void attn_kernel(const bf16_t* __restrict__ qh,
                                                      const bf16_t* __restrict__ kh,
                                                      const bf16_t* __restrict__ vh,
                                                      const float* __restrict__ bias,
                                                      bf16_t* __restrict__ o) {
  __shared__ __align__(16) bf16_t Pl[4][64 * 68];
  __shared__ __align__(16) bf16_t Vt[4][32 * 72];
  const int tid = threadIdx.x;
  const int lane = tid & 63, lo = lane & 15, hi = lane >> 4;
  const int w = tid >> 6;                   // 0..7
  const int wh = w >> 1, sub = w & 1;       // window-head slot, row-half
  const int id = (blockIdx.x << 2) + wh;    // 0..16383
  const int win = id >> 3, h = id & 7;
  const size_t hb = ((size_t)h * MROWS + (size_t)win * 64) * 32;
  const bf16_t* qb = qh + hb;
  const bf16_t* kb = kh + hb;
  const bf16_t* vb = vh + hb;

  // stage V transposed: wave covers tokens m = sub*32 .. +31, both d-halves
  {
    int m  = (sub << 5) + (lane & 31);
    int dh = (lane >> 5) << 4;              // 0 | 16
    const bf16_t* vp = vb + (size_t)m * 32 + dh;
    bf16x8 v0 = *reinterpret_cast<const bf16x8*>(vp);
    bf16x8 v1 = *reinterpret_cast<const bf16x8*>(vp + 8);
#pragma unroll
    for (int e = 0; e < 8; ++e) {
      Vt[wh][(dh + e) * 72 + m]     = v0[e];
      Vt[wh][(dh + 8 + e) * 72 + m] = v1[e];
    }
  }

  // QK^T: rows n = sub*32 .. +31 (2 frags), all 64 K rows (4 frags)
  bf16x8 qa[2], ka[4];
#pragma unroll
  for (int il = 0; il < 2; ++il)
    qa[il] = *reinterpret_cast<const bf16x8*>(qb + ((sub << 5) + (il << 4) + lo) * 32 + (hi << 3));
#pragma unroll
  for (int j = 0; j < 4; ++j)
    ka[j] = *reinterpret_cast<const bf16x8*>(kb + ((j << 4) + lo) * 32 + (hi << 3));
  f32x4 s4[2][4] = {};
#pragma unroll
  for (int il = 0; il < 2; ++il)
#pragma unroll
    for (int j = 0; j < 4; ++j) s4[il][j] = mfma16(qa[il], ka[j], s4[il][j]);

  const int whw = (win & 63) >> 3, www = win & 7;
  const int cls = ((whw == 7) ? 2 : 0) + ((www == 7) ? 1 : 0);
  const float* bb = bias + ((size_t)cls * 8 + h) * 4096;
  const float scale = 0.17677669529663687f;  // 1/sqrt(32)

  float pinv[2][4];
#pragma unroll
  for (int il = 0; il < 2; ++il) {
#pragma unroll
    for (int r = 0; r < 4; ++r) {
      int n = (sub << 5) + (il << 4) + (hi << 2) + r;
      const float* brow = bb + n * 64 + lo;
      float vals[4], mx = -1e30f;
#pragma unroll
      for (int j = 0; j < 4; ++j) {
        float val = s4[il][j][r] * scale + brow[j << 4];
        vals[j] = val;
        mx = fmaxf(mx, val);
      }
#pragma unroll
      for (int d = 1; d < 16; d <<= 1) mx = fmaxf(mx, __shfl_xor(mx, d));
      float sum = 0.0f;
#pragma unroll
      for (int j = 0; j < 4; ++j) {
        float p = __expf(vals[j] - mx);
        sum += p;
        Pl[wh][n * 68 + (j << 4) + lo] = to_bf16(p);
      }
#pragma unroll
      for (int d = 1; d < 16; d <<= 1) sum += __shfl_xor(sum, d);
      pinv[il][r] = 1.0f / sum;
    }
  }

  __syncthreads();   // Vt + Pl complete (pair + block)

  // PV: O[own 32, 32] = P[own 32, 64] @ V[64, 32]
  f32x4 oa[2][2] = {};
#pragma unroll
  for (int kt = 0; kt < 2; ++kt) {
    bf16x8 pa[2], va[2];
#pragma unroll
    for (int il = 0; il < 2; ++il)
      pa[il] = *reinterpret_cast<const bf16x8*>(&Pl[wh][((sub << 5) + (il << 4) + lo) * 68 + (kt << 5) + (hi << 3)]);
#pragma unroll
    for (int dt = 0; dt < 2; ++dt)
      va[dt] = *reinterpret_cast<const bf16x8*>(&Vt[wh][((dt << 4) + lo) * 72 + (kt << 5) + (hi << 3)]);
#pragma unroll
    for (int il = 0; il < 2; ++il)
#pragma unroll
      for (int dt = 0; dt < 2; ++dt) oa[il][dt] = mfma16(pa[il], va[dt], oa[il][dt]);
  }

  bf16_t* ob = o + (size_t)win * (64 * 256) + h * 32;
#pragma unroll
  for (int il = 0; il < 2; ++il)
#pragma unroll
    for (int r = 0; r < 4; ++r) {
      int n = (sub << 5) + (il << 4) + (hi << 2) + r;
      float piv = pinv[il][r];
#pragma unroll
      for (int dt = 0; dt < 2; ++dt)
        ob[(size_t)n * 256 + (dt << 4) + lo] = to_bf16(oa[il][dt][r] * piv);
    }
}

// ---------------- launch ----------------
extern "C" void kernel_launch(void* const* d_in, const int* in_sizes, int n_in,
                              void* d_out, int out_size, void* d_ws, size_t ws_size,
                              hipStream_t stream) {
  const float* x      = (const float*)d_in[0];
  const float* n1g    = (const float*)d_in[1];
  const float* n1b    = (const float*)d_in[2];
  const float* qkv_w  = (const float*)d_in[3];
  const float* qkv_b  = (const float*)d_in[4];
  const float* rpbt   = (const float*)d_in[5];
  const float* proj_w = (const float*)d_in[6];
  const float* proj_b = (const float*)d_in[7];
  const float* n2g    = (const float*)d_in[8];
  const float* n2b    = (const float*)d_in[9];
  const float* fc1_w  = (const float*)d_in[10];
  const float* fc1_b  = (const float*)d_in[11];
  const float* fc2_w  = (const float*)d_in[12];
  const float* fc2_b  = (const float*)d_in[13];
  float* out = (float*)d_out;
  char*  ws  = (char*)d_ws;

  // ws: [0,64Mi) hln -> obuf -> h2 chunk | [64Mi,128Mi) qbuf -> x2n | [128Mi..] weights+bias
  // d_out doubles as scratch: k,v bf16 (head-major) until proj, then x2/out fp32.
  const size_t MB64 = 67108864;
  bf16_t* hln  = (bf16_t*)(ws);
  bf16_t* obuf = (bf16_t*)(ws);
  bf16_t* h2   = (bf16_t*)(ws);
  bf16_t* qbuf = (bf16_t*)(ws + MB64);
  bf16_t* x2n  = (bf16_t*)(ws + MB64);
  bf16_t* wb   = (bf16_t*)(ws + 2 * MB64);
  bf16_t* qkv_wb  = wb;                   // 196608 el
  bf16_t* proj_wb = qkv_wb + 196608;      // 65536
  bf16_t* fc1_wb  = proj_wb + 65536;      // 262144
  bf16_t* fc2_wb  = fc1_wb + 262144;      // 262144
  float*  biast   = (float*)(fc2_wb + 262144);  // 131072 f32 = 512KB
  bf16_t* kbuf = (bf16_t*)d_out;          // 33554432 el (64MiB)
  bf16_t* vbuf = kbuf + 33554432;

  const int SMEM_G = 49152;               // 2x(As 8KB + Bs 16KB)
  const int SMEM_P = 54272;               // + LN scratch (EPI2)
  hipFuncSetAttribute(reinterpret_cast<const void*>(gemm128x256<1>),
                      hipFuncAttributeMaxDynamicSharedMemorySize, SMEM_G);
  hipFuncSetAttribute(reinterpret_cast<const void*>(gemm128x256<2>),
                      hipFuncAttributeMaxDynamicSharedMemorySize, SMEM_P);
  hipFuncSetAttribute(reinterpret_cast<const void*>(gemm128x256<4>),
                      hipFuncAttributeMaxDynamicSharedMemorySize, SMEM_G);

  cvt_all<<<3072, 256, 0, stream>>>(qkv_w, proj_w, fc1_w, fc2_w,
                                    qkv_wb, proj_wb, fc1_wb, fc2_wb);
  bias_kernel<<<512, 256, 0, stream>>>(rpbt, biast);

  // LN1 + shift + window partition
  ln_kernel<true><<<32768, 256, 0, stream>>>(x, n1g, n1b, hln);

  // fused QKV -> head-major q/k/v (nwg = 1024*3 = 3072, %8==0)
  gemm128x256<4><<<3072, 512, SMEM_G, stream>>>(hln, qkv_wb, qkv_b, qbuf, kbuf, vbuf,
                                                nullptr, nullptr, nullptr, nullptr,
                                                MROWS, 768, 256, 3);

  // windowed attention (4 window-heads per 512-thread block)
  attn_kernel<<<4096, 512, 0, stream>>>(qbuf, kbuf, vbuf, biast, obuf);

  // proj + reverse-scatter + residual -> x2 fp32 in d_out, FUSED LN2 -> x2n (nwg=1024)
  gemm128x256<2><<<1024, 512, SMEM_P, stream>>>(obuf, proj_wb, proj_b, out, nullptr, nullptr,
                                                x, n2g, n2b, x2n, MROWS, 256, 256, 1);

  // MLP in 4 row-chunks (h2 chunk = 32768 x 1024 bf16 = 64MB, L3-resident)
  for (int c = 0; c < 4; ++c) {
    const bf16_t* xa = x2n + (size_t)c * 32768 * 256;
    gemm128x256<1><<<1024, 512, SMEM_G, stream>>>(xa, fc1_wb, fc1_b, h2, nullptr, nullptr,
                                                  nullptr, nullptr, nullptr, nullptr,
                                                  32768, 1024, 256, 4);
    gemm_bt<3><<<512, 256, 0, stream>>>(h2, fc2_wb, fc2_b, out + (size_t)c * 32768 * 256,
                                        32768, 256, 1024, 2);
  }
}

// Round 15
// 659.141 us; speedup vs baseline: 2.7898x; 2.7898x over previous
//
#include <hip/hip_runtime.h>
#include <hip/hip_bf16.h>
#include <stdint.h>

typedef __bf16 bf16_t;
typedef __bf16 bf16x8 __attribute__((ext_vector_type(8)));
typedef __bf16 bf16x4 __attribute__((ext_vector_type(4)));
typedef float f32x4 __attribute__((ext_vector_type(4)));

// Problem constants: B=32, H=W=64, C=256, heads=8, ws=8, ss=4
#define MROWS 131072   // B * 64 * 64 tokens (window layout rows)

__device__ __forceinline__ bf16_t to_bf16(float f) {
  __hip_bfloat16 h = __float2bfloat16(f);   // RNE
  return *reinterpret_cast<bf16_t*>(&h);
}

__device__ __forceinline__ f32x4 mfma16(bf16x8 a, bf16x8 b, f32x4 c) {
  return __builtin_amdgcn_mfma_f32_16x16x32_bf16(a, b, c, 0, 0, 0);
}

__device__ __forceinline__ void gload16(const void* g, void* l) {
  __builtin_amdgcn_global_load_lds(
      (const __attribute__((address_space(1))) void*)g,
      (__attribute__((address_space(3))) void*)l, 16, 0, 0);
}

// window-layout row m  ->  x row (shift+partition gather; reverse+unshift scatter)
__device__ __forceinline__ int map_row(int m) {
  int b   = m >> 12;
  int rem = m & 4095;
  int win = rem >> 6;
  int n   = rem & 63;
  int gh  = ((win >> 3) << 3) + (n >> 3);
  int gw  = ((win & 7) << 3) + (n & 7);
  int sh  = (gh + 4) & 63;
  int sw  = (gw + 4) & 63;
  return (b << 12) + (sh << 6) + sw;
}

// ---------------- fp32 -> bf16 weight convert (all 4 weight mats, one launch) ------
__global__ __launch_bounds__(256) void cvt_all(const float* __restrict__ qkv_w,
                                               const float* __restrict__ proj_w,
                                               const float* __restrict__ fc1_w,
                                               const float* __restrict__ fc2_w,
                                               bf16_t* __restrict__ qkv_o,
                                               bf16_t* __restrict__ proj_o,
                                               bf16_t* __restrict__ fc1_o,
                                               bf16_t* __restrict__ fc2_o) {
  int i = blockIdx.x * 256 + threadIdx.x;   // 0 .. 786431
  if (i < 196608)       qkv_o[i] = to_bf16(qkv_w[i]);
  else if (i < 262144)  proj_o[i - 196608] = to_bf16(proj_w[i - 196608]);
  else if (i < 524288)  fc1_o[i - 262144] = to_bf16(fc1_w[i - 262144]);
  else                  fc2_o[i - 524288] = to_bf16(fc2_w[i - 524288]);
}

// ---------------- bias table: bias[cls][h][n][m] = rpb(n,m,h) + mask(cls,n,m) ------
__global__ __launch_bounds__(256) void bias_kernel(const float* __restrict__ rpbt,
                                                   float* __restrict__ bias) {
  int idx = blockIdx.x * 256 + threadIdx.x;   // 0 .. 131071
  int m = idx & 63, n = (idx >> 6) & 63, h = (idx >> 12) & 7, c = idx >> 15;
  int yn = n >> 3, xn = n & 7, ym = m >> 3, xm = m & 7;
  float v = rpbt[((yn - ym + 7) * 15 + (xn - xm + 7)) * 8 + h];
  int rn = (c & 2) ? (yn < 4 ? 1 : 2) : 0;
  int cn = (c & 1) ? (xn < 4 ? 1 : 2) : 0;
  int rm = (c & 2) ? (ym < 4 ? 1 : 2) : 0;
  int cm = (c & 1) ? (xm < 4 ? 1 : 2) : 0;
  if (rn * 3 + cn != rm * 3 + cm) v -= 100.0f;
  bias[idx] = v;
}

// ---------------- LayerNorm (wave per row), row-permuted gather (LN1) ----------------
template <bool PERM>
__global__ __launch_bounds__(256) void ln_kernel(const float* __restrict__ xin,
                                                 const float* __restrict__ g,
                                                 const float* __restrict__ b,
                                                 bf16_t* __restrict__ out) {
  int row  = (blockIdx.x << 2) + (threadIdx.x >> 6);
  int lane = threadIdx.x & 63;
  int src  = PERM ? map_row(row) : row;
  float4 v = *reinterpret_cast<const float4*>(xin + (size_t)src * 256 + (lane << 2));
  float s = v.x + v.y + v.z + v.w;
#pragma unroll
  for (int d = 1; d < 64; d <<= 1) s += __shfl_xor(s, d);
  float mean = s * 0.00390625f;
  float ax = v.x - mean, ay = v.y - mean, az = v.z - mean, aw = v.w - mean;
  float s2 = ax * ax + ay * ay + az * az + aw * aw;
#pragma unroll
  for (int d = 1; d < 64; d <<= 1) s2 += __shfl_xor(s2, d);
  float rstd = rsqrtf(s2 * 0.00390625f + 1e-5f);
  float4 gv = *reinterpret_cast<const float4*>(g + (lane << 2));
  float4 bv = *reinterpret_cast<const float4*>(b + (lane << 2));
  bf16x4 o4;
  o4[0] = to_bf16(ax * rstd * gv.x + bv.x);
  o4[1] = to_bf16(ay * rstd * gv.y + bv.y);
  o4[2] = to_bf16(az * rstd * gv.z + bv.z);
  o4[3] = to_bf16(aw * rstd * gv.w + bv.w);
  *reinterpret_cast<bf16x4*>(out + (size_t)row * 256 + (lane << 2)) = o4;
}

// ======== 128(M)x256(N)-tile, 8 waves (2Mx4N), BK=32 ========
// DOUBLE-buffered LDS (48KB) + depth-2 cross-barrier staging:
//   compute(t) -> s_barrier (buf dead) -> STG(t+2 into freed buf) -> vmcnt(3)
//   (retires t+1; t+2 flies across the barrier) -> s_barrier.
// launch_bounds(512,4): VGPR cap 128 (r14's (512,6) cap=85 caused catastrophic
// spill: VGPR 40, 2.4GB scratch traffic/dispatch). 48KB LDS allows 3 blocks/CU
// if the allocator stays <=85 naturally (r13 used 64).
// T2 swizzle both-sides; T1 XCD swizzle; T5 setprio.
// EPI 1: GELU -> bf16 via two-pass LDS-bounce (h2)
// EPI 2: proj: fp32 permuted store + resid + FUSED LN2 -> x2n
// EPI 4: qkv head-major split via two-pass LDS-bounce
template <int EPI>
__global__ __launch_bounds__(512, 4) void gemm128x256(const bf16_t* __restrict__ A,
                                                      const bf16_t* __restrict__ W,
                                                      const float* __restrict__ bias,
                                                      void* __restrict__ outp,
                                                      void* __restrict__ outp2,
                                                      void* __restrict__ outp3,
                                                      const float* __restrict__ resid,
                                                      const float* __restrict__ n2g,
                                                      const float* __restrict__ n2b,
                                                      bf16_t* __restrict__ x2n,
                                                      int M, int N, int K, int NBN) {
  extern __shared__ __align__(16) char smem[];
  bf16_t* As  = (bf16_t*)smem;              // [2][128*32]  (16 KB)
  bf16_t* Bs  = As + 2 * 4096;              // [2][256*32]  (32 KB)
  float*  lnS = (float*)(Bs + 2 * 8192);    // EPI2: [128][4]
  float*  lnQ = lnS + 512;                  // [128][4]
  float*  lnMR = lnQ + 512;                 // [128][2]
  const int tid  = threadIdx.x;
  const int lane = tid & 63, lo = lane & 15, hi = lane >> 4;
  const int wid  = tid >> 6, wm = wid >> 2, wn = wid & 3;
  const int cpx = gridDim.x >> 3;           // T1 XCD chunk swizzle
  const int wg  = (blockIdx.x & 7) * cpx + (blockIdx.x >> 3);
  const int bn = (wg % NBN) << 8, bm = (wg / NBN) << 7;
  f32x4 acc[4][4] = {};

  // STAGE one K-tile: 3 gloads/thread (A:1, B:2); source 16B-slot pre-swizzled (T2)
#define STG(buf, kt)                                                          \
  {                                                                           \
    int k0s = (kt) << 5;                                                      \
    {                                                                         \
      int ch = tid;                                                           \
      int row = ch >> 2, sl = ((ch & 3) ^ ((row >> 1) & 3)) << 3;             \
      gload16(A + (size_t)(bm + row) * K + k0s + sl,                          \
              &As[((buf) << 12) + (ch << 3)]);                                \
    }                                                                         \
    _Pragma("unroll") for (int l = 0; l < 2; ++l) {                           \
      int ch = (l << 9) + tid;                                                \
      int row = ch >> 2, sl = ((ch & 3) ^ ((row >> 1) & 3)) << 3;             \
      gload16(W + (size_t)(bn + row) * K + k0s + sl,                          \
              &Bs[((buf) << 13) + (ch << 3)]);                                \
    }                                                                         \
  }

  const int nt = K >> 5;                    // 8 (K=256)
  STG(0, 0);
  STG(1, 1);                                // 6 loads/thread outstanding
  asm volatile("s_waitcnt vmcnt(3)" ::: "memory");   // tile 0 landed (tile 1 flying)
  __builtin_amdgcn_s_barrier();

  for (int t = 0; t < nt; ++t) {
    const int cur = t & 1;
    const bf16_t* as = &As[cur << 12];
    const bf16_t* bs = &Bs[cur << 13];
    bf16x8 af[4], bfr[4];
#pragma unroll
    for (int i = 0; i < 4; ++i) {
      int ra = (wm << 6) + (i << 4) + lo;
      af[i] = *reinterpret_cast<const bf16x8*>(&as[ra * 32 + ((hi ^ ((ra >> 1) & 3)) << 3)]);
    }
#pragma unroll
    for (int j = 0; j < 4; ++j) {
      int rb = (wn << 6) + (j << 4) + lo;
      bfr[j] = *reinterpret_cast<const bf16x8*>(&bs[rb * 32 + ((hi ^ ((rb >> 1) & 3)) << 3)]);
    }
    __builtin_amdgcn_s_setprio(1);          // T5
#pragma unroll
    for (int i = 0; i < 4; ++i)
#pragma unroll
      for (int j = 0; j < 4; ++j)
        acc[i][j] = mfma16(af[i], bfr[j], acc[i][j]);
    __builtin_amdgcn_s_setprio(0);
    if (t + 1 < nt) {
      __builtin_amdgcn_s_barrier();         // all waves done reading buf cur
      if (t + 2 < nt) {
        STG(cur, t + 2);                    // refill freed buf; flies across barrier
        asm volatile("s_waitcnt vmcnt(3)" ::: "memory");   // t+1 retired
      } else {
        asm volatile("s_waitcnt vmcnt(0)" ::: "memory");
      }
      __builtin_amdgcn_s_barrier();         // tile t+1 visible everywhere
    }
  }
#undef STG

  float bv4[4];
#pragma unroll
  for (int nf = 0; nf < 4; ++nf) bv4[nf] = bias[bn + (wn << 6) + (nf << 4) + lo];

  if constexpr (EPI == 2) {
    // proj epilogue (BN = N = 256: full rows in-block): x2 = resid + o + b -> out
    // (permuted rows, fp32), then fused LN2 -> x2n bf16.
    float* o = (float*)outp;
    float gv[4], bnv[4];
#pragma unroll
    for (int nf = 0; nf < 4; ++nf) {
      int col = (wn << 6) + (nf << 4) + lo;
      gv[nf] = n2g[col]; bnv[nf] = n2b[col];
    }
#pragma unroll
    for (int mf = 0; mf < 4; ++mf)
#pragma unroll
      for (int r = 0; r < 4; ++r) {
        int rl = (wm << 6) + (mf << 4) + (hi << 2) + r;   // 0..127
        int xr = map_row(bm + rl);
        float s = 0.f, q = 0.f;
#pragma unroll
        for (int nf = 0; nf < 4; ++nf) {
          int col = (wn << 6) + (nf << 4) + lo;
          size_t idx = (size_t)xr * 256 + col;
          float v = resid[idx] + acc[mf][nf][r] + bv4[nf];
          acc[mf][nf][r] = v;
          o[idx] = v;
          s += v; q += v * v;
        }
#pragma unroll
        for (int d = 1; d < 16; d <<= 1) { s += __shfl_xor(s, d); q += __shfl_xor(q, d); }
        if (lo == 0) { lnS[(rl << 2) + wn] = s; lnQ[(rl << 2) + wn] = q; }
      }
    __syncthreads();
    if (tid < 128) {
      float s = lnS[tid << 2] + lnS[(tid << 2) + 1] + lnS[(tid << 2) + 2] + lnS[(tid << 2) + 3];
      float q = lnQ[tid << 2] + lnQ[(tid << 2) + 1] + lnQ[(tid << 2) + 2] + lnQ[(tid << 2) + 3];
      float mean = s * 0.00390625f;
      float var  = q * 0.00390625f - mean * mean;
      lnMR[tid << 1] = mean;
      lnMR[(tid << 1) + 1] = rsqrtf(var + 1e-5f);
    }
    __syncthreads();
#pragma unroll
    for (int mf = 0; mf < 4; ++mf)
#pragma unroll
      for (int r = 0; r < 4; ++r) {
        int rl = (wm << 6) + (mf << 4) + (hi << 2) + r;
        int xr = map_row(bm + rl);
        float mean = lnMR[rl << 1], rstd = lnMR[(rl << 1) + 1];
#pragma unroll
        for (int nf = 0; nf < 4; ++nf) {
          int col = (wn << 6) + (nf << 4) + lo;
          x2n[(size_t)xr * 256 + col] = to_bf16((acc[mf][nf][r] - mean) * rstd * gv[nf] + bnv[nf]);
        }
      }
  } else if constexpr (EPI == 4) {
    // QKV: two-pass LDS-bounce (Os[64][264] fits the 48KB buffers); wave wid
    // streams head wid's contiguous 4KB run per pass.
    bf16_t* base = (bn == 0) ? (bf16_t*)outp
                 : (bn == 256) ? (bf16_t*)outp2 : (bf16_t*)outp3;
    bf16_t* Os = (bf16_t*)smem;             // [64][264] = 33.8 KB
#pragma unroll
    for (int pass = 0; pass < 2; ++pass) {
      __syncthreads();                      // buffers dead / prev pass streamed
      if (wm == pass) {
#pragma unroll
        for (int mf = 0; mf < 4; ++mf)
#pragma unroll
          for (int r = 0; r < 4; ++r) {
            int rl = (mf << 4) + (hi << 2) + r;   // local 0..63
#pragma unroll
            for (int nf = 0; nf < 4; ++nf) {
              int col = (wn << 6) + (nf << 4) + lo;
              Os[rl * 264 + col] = to_bf16(acc[mf][nf][r] + bv4[nf]);
            }
          }
      }
      __syncthreads();
      bf16_t* dst = base + ((size_t)wid * MROWS + bm + (pass << 6)) * 32;
#pragma unroll
      for (int p = 0; p < 4; ++p) {
        int off = (p << 9) + (lane << 3);   // 0..2047 el (64 rows x 32)
        int row = off >> 5, d0 = off & 31;
        bf16x8 vv = *reinterpret_cast<const bf16x8*>(&Os[row * 264 + (wid << 5) + d0]);
        *reinterpret_cast<bf16x8*>(dst + off) = vv;
      }
    }
  } else {
    // EPI 1: GELU -> bf16 via two-pass LDS-bounce, coalesced row-major store (h2)
    bf16_t* o = (bf16_t*)outp;
    bf16_t* Os = (bf16_t*)smem;             // [64][264]
#pragma unroll
    for (int pass = 0; pass < 2; ++pass) {
      __syncthreads();
      if (wm == pass) {
#pragma unroll
        for (int mf = 0; mf < 4; ++mf)
#pragma unroll
          for (int r = 0; r < 4; ++r) {
            int rl = (mf << 4) + (hi << 2) + r;   // local 0..63
#pragma unroll
            for (int nf = 0; nf < 4; ++nf) {
              int col = (wn << 6) + (nf << 4) + lo;
              float v = acc[mf][nf][r] + bv4[nf];
              if constexpr (EPI == 1) v = 0.5f * v * (1.0f + erff(v * 0.70710678118654752f));
              Os[rl * 264 + col] = to_bf16(v);
            }
          }
      }
      __syncthreads();
#pragma unroll
      for (int p = 0; p < 4; ++p) {
        int off = (p << 9) + (lane << 3);   // wave's 8 rows x 256 cols
        int row = (wid << 3) + (off >> 8);  // 0..63
        int col = off & 255;
        bf16x8 vv = *reinterpret_cast<const bf16x8*>(&Os[row * 264 + col]);
        *reinterpret_cast<bf16x8*>(o + (size_t)(bm + (pass << 6) + row) * N + bn + col) = vv;
      }
    }
  }
}

// ---------------- 128x128 bf16 GEMM, 3-stage counted-vmcnt (r8 proven) — FC2 ------
template <int EPI>
__global__ __launch_bounds__(256) void gemm_bt(const bf16_t* __restrict__ A,
                                               const bf16_t* __restrict__ W,
                                               const float* __restrict__ bias,
                                               void* __restrict__ outp,
                                               int M, int N, int K, int NBN) {
  __shared__ __align__(16) bf16_t As[3 * 128 * 32];
  __shared__ __align__(16) bf16_t Bs[3 * 128 * 32];
  const int tid  = threadIdx.x;
  const int lane = tid & 63, lo = lane & 15, hi = lane >> 4;
  const int wave = tid >> 6;
  const int cpx = gridDim.x >> 3;
  const int wg  = (blockIdx.x & 7) * cpx + (blockIdx.x >> 3);
  const int bn = (wg % NBN) << 7, bm = (wg / NBN) << 7;
  const int wr = (wave >> 1) << 6, wc = (wave & 1) << 6;
  f32x4 acc[4][4] = {};

#define STAGE(buf, kt)                                                         \
  {                                                                            \
    int k0s = (kt) << 5;                                                       \
    _Pragma("unroll") for (int it = 0; it < 2; ++it) {                         \
      int ch = (it << 8) + tid;                                                \
      int r = ch >> 2;                                                         \
      int kf = ((ch & 3) ^ ((r >> 1) & 3)) << 3;                               \
      gload16(A + (size_t)(bm + r) * K + k0s + kf, &As[((buf) << 12) + (ch << 3)]); \
      gload16(W + (size_t)(bn + r) * K + k0s + kf, &Bs[((buf) << 12) + (ch << 3)]); \
    }                                                                          \
  }

  const int nt = K >> 5;
  STAGE(0, 0);
  STAGE(1, 1);

  int cb = 0;
  for (int t = 0; t < nt; ++t) {
    if (t + 1 < nt) { asm volatile("s_waitcnt vmcnt(4)" ::: "memory"); }
    else            { asm volatile("s_waitcnt vmcnt(0)" ::: "memory"); }
    __builtin_amdgcn_s_barrier();
    if (t + 2 < nt) {
      int sb = (cb == 0) ? 2 : cb - 1;
      STAGE(sb, t + 2);
    }
    const bf16_t* as = &As[cb << 12];
    const bf16_t* bs = &Bs[cb << 12];
    bf16x8 af[4], bfr[4];
#pragma unroll
    for (int i = 0; i < 4; ++i) {
      int ra = wr + (i << 4) + lo;
      af[i] = *reinterpret_cast<const bf16x8*>(&as[ra * 32 + ((hi ^ ((ra >> 1) & 3)) << 3)]);
    }
#pragma unroll
    for (int j = 0; j < 4; ++j) {
      int rb = wc + (j << 4) + lo;
      bfr[j] = *reinterpret_cast<const bf16x8*>(&bs[rb * 32 + ((hi ^ ((rb >> 1) & 3)) << 3)]);
    }
    __builtin_amdgcn_s_setprio(1);
#pragma unroll
    for (int i = 0; i < 4; ++i)
#pragma unroll
      for (int j = 0; j < 4; ++j)
        acc[i][j] = mfma16(af[i], bfr[j], acc[i][j]);
    __builtin_amdgcn_s_setprio(0);
    cb = (cb == 2) ? 0 : cb + 1;
  }
#undef STAGE

  float bv[4];
#pragma unroll
  for (int j = 0; j < 4; ++j) bv[j] = bias[bn + wc + (j << 4) + lo];

#pragma unroll
  for (int i = 0; i < 4; ++i)
#pragma unroll
    for (int r = 0; r < 4; ++r) {
      int row = bm + wr + (i << 4) + (hi << 2) + r;
      float* o = (float*)outp;   // EPI 3 only
#pragma unroll
      for (int j = 0; j < 4; ++j) {
        int col = bn + wc + (j << 4) + lo;
        size_t idx = (size_t)row * 256 + col;
        o[idx] = o[idx] + acc[i][j][r] + bv[j];
      }
    }
}

// ---------------- windowed attention v2: wave PAIR per (window, head) ----------------
// Pl stride 68; launch_bounds(512,4) (cap 128 — attn needs ~88 VGPR; (512,6)'s
// cap 85 would spill).
__global__ __launch_bounds__(512, 4) void attn_kernel(const bf16_t* __restrict__ qh,
                                                      const bf16_t* __restrict__ kh,
                                                      const bf16_t* __restrict__ vh,
                                                      const float* __restrict__ bias,
                                                      bf16_t* __restrict__ o) {
  __shared__ __align__(16) bf16_t Pl[4][64 * 68];
  __shared__ __align__(16) bf16_t Vt[4][32 * 72];
  const int tid = threadIdx.x;
  const int lane = tid & 63, lo = lane & 15, hi = lane >> 4;
  const int w = tid >> 6;                   // 0..7
  const int wh = w >> 1, sub = w & 1;       // window-head slot, row-half
  const int id = (blockIdx.x << 2) + wh;    // 0..16383
  const int win = id >> 3, h = id & 7;
  const size_t hb = ((size_t)h * MROWS + (size_t)win * 64) * 32;
  const bf16_t* qb = qh + hb;
  const bf16_t* kb = kh + hb;
  const bf16_t* vb = vh + hb;

  // stage V transposed: wave covers tokens m = sub*32 .. +31, both d-halves
  {
    int m  = (sub << 5) + (lane & 31);
    int dh = (lane >> 5) << 4;              // 0 | 16
    const bf16_t* vp = vb + (size_t)m * 32 + dh;
    bf16x8 v0 = *reinterpret_cast<const bf16x8*>(vp);
    bf16x8 v1 = *reinterpret_cast<const bf16x8*>(vp + 8);
#pragma unroll
    for (int e = 0; e < 8; ++e) {
      Vt[wh][(dh + e) * 72 + m]     = v0[e];
      Vt[wh][(dh + 8 + e) * 72 + m] = v1[e];
    }
  }

  // QK^T: rows n = sub*32 .. +31 (2 frags), all 64 K rows (4 frags)
  bf16x8 qa[2], ka[4];
#pragma unroll
  for (int il = 0; il < 2; ++il)
    qa[il] = *reinterpret_cast<const bf16x8*>(qb + ((sub << 5) + (il << 4) + lo) * 32 + (hi << 3));
#pragma unroll
  for (int j = 0; j < 4; ++j)
    ka[j] = *reinterpret_cast<const bf16x8*>(kb + ((j << 4) + lo) * 32 + (hi << 3));
  f32x4 s4[2][4] = {};
#pragma unroll
  for (int il = 0; il < 2; ++il)
#pragma unroll
    for (int j = 0; j < 4; ++j) s4[il][j] = mfma16(qa[il], ka[j], s4[il][j]);

  const int whw = (win & 63) >> 3, www = win & 7;
  const int cls = ((whw == 7) ? 2 : 0) + ((www == 7) ? 1 : 0);
  const float* bb = bias + ((size_t)cls * 8 + h) * 4096;
  const float scale = 0.17677669529663687f;  // 1/sqrt(32)

  float pinv[2][4];
#pragma unroll
  for (int il = 0; il < 2; ++il) {
#pragma unroll
    for (int r = 0; r < 4; ++r) {
      int n = (sub << 5) + (il << 4) + (hi << 2) + r;
      const float* brow = bb + n * 64 + lo;
      float vals[4], mx = -1e30f;
#pragma unroll
      for (int j = 0; j < 4; ++j) {
        float val = s4[il][j][r] * scale + brow[j << 4];
        vals[j] = val;
        mx = fmaxf(mx, val);
      }
#pragma unroll
      for (int d = 1; d < 16; d <<= 1) mx = fmaxf(mx, __shfl_xor(mx, d));
      float sum = 0.0f;
#pragma unroll
      for (int j = 0; j < 4; ++j) {
        float p = __expf(vals[j] - mx);
        sum += p;
        Pl[wh][n * 68 + (j << 4) + lo] = to_bf16(p);
      }
#pragma unroll
      for (int d = 1; d < 16; d <<= 1) sum += __shfl_xor(sum, d);
      pinv[il][r] = 1.0f / sum;
    }
  }

  __syncthreads();   // Vt + Pl complete (pair + block)

  // PV: O[own 32, 32] = P[own 32, 64] @ V[64, 32]
  f32x4 oa[2][2] = {};
#pragma unroll
  for (int kt = 0; kt < 2; ++kt) {
    bf16x8 pa[2], va[2];
#pragma unroll
    for (int il = 0; il < 2; ++il)
      pa[il] = *reinterpret_cast<const bf16x8*>(&Pl[wh][((sub << 5) + (il << 4) + lo) * 68 + (kt << 5) + (hi << 3)]);
#pragma unroll
    for (int dt = 0; dt < 2; ++dt)
      va[dt] = *reinterpret_cast<const bf16x8*>(&Vt[wh][((dt << 4) + lo) * 72 + (kt << 5) + (hi << 3)]);
#pragma unroll
    for (int il = 0; il < 2; ++il)
#pragma unroll
      for (int dt = 0; dt < 2; ++dt) oa[il][dt] = mfma16(pa[il], va[dt], oa[il][dt]);
  }

  bf16_t* ob = o + (size_t)win * (64 * 256) + h * 32;
#pragma unroll
  for (int il = 0; il < 2; ++il)
#pragma unroll
    for (int r = 0; r < 4; ++r) {
      int n = (sub << 5) + (il << 4) + (hi << 2) + r;
      float piv = pinv[il][r];
#pragma unroll
      for (int dt = 0; dt < 2; ++dt)
        ob[(size_t)n * 256 + (dt << 4) + lo] = to_bf16(oa[il][dt][r] * piv);
    }
}

// ---------------- launch ----------------
extern "C" void kernel_launch(void* const* d_in, const int* in_sizes, int n_in,
                              void* d_out, int out_size, void* d_ws, size_t ws_size,
                              hipStream_t stream) {
  const float* x      = (const float*)d_in[0];
  const float* n1g    = (const float*)d_in[1];
  const float* n1b    = (const float*)d_in[2];
  const float* qkv_w  = (const float*)d_in[3];
  const float* qkv_b  = (const float*)d_in[4];
  const float* rpbt   = (const float*)d_in[5];
  const float* proj_w = (const float*)d_in[6];
  const float* proj_b = (const float*)d_in[7];
  const float* n2g    = (const float*)d_in[8];
  const float* n2b    = (const float*)d_in[9];
  const float* fc1_w  = (const float*)d_in[10];
  const float* fc1_b  = (const float*)d_in[11];
  const float* fc2_w  = (const float*)d_in[12];
  const float* fc2_b  = (const float*)d_in[13];
  float* out = (float*)d_out;
  char*  ws  = (char*)d_ws;

  // ws: [0,64Mi) hln -> obuf -> h2 chunk | [64Mi,128Mi) qbuf -> x2n | [128Mi..] weights+bias
  // d_out doubles as scratch: k,v bf16 (head-major) until proj, then x2/out fp32.
  const size_t MB64 = 67108864;
  bf16_t* hln  = (bf16_t*)(ws);
  bf16_t* obuf = (bf16_t*)(ws);
  bf16_t* h2   = (bf16_t*)(ws);
  bf16_t* qbuf = (bf16_t*)(ws + MB64);
  bf16_t* x2n  = (bf16_t*)(ws + MB64);
  bf16_t* wb   = (bf16_t*)(ws + 2 * MB64);
  bf16_t* qkv_wb  = wb;                   // 196608 el
  bf16_t* proj_wb = qkv_wb + 196608;      // 65536
  bf16_t* fc1_wb  = proj_wb + 65536;      // 262144
  bf16_t* fc2_wb  = fc1_wb + 262144;      // 262144
  float*  biast   = (float*)(fc2_wb + 262144);  // 131072 f32 = 512KB
  bf16_t* kbuf = (bf16_t*)d_out;          // 33554432 el (64MiB)
  bf16_t* vbuf = kbuf + 33554432;

  const int SMEM_G = 49152;               // 2x(As 8KB + Bs 16KB)
  const int SMEM_P = 54272;               // + LN scratch (EPI2)
  hipFuncSetAttribute(reinterpret_cast<const void*>(gemm128x256<1>),
                      hipFuncAttributeMaxDynamicSharedMemorySize, SMEM_G);
  hipFuncSetAttribute(reinterpret_cast<const void*>(gemm128x256<2>),
                      hipFuncAttributeMaxDynamicSharedMemorySize, SMEM_P);
  hipFuncSetAttribute(reinterpret_cast<const void*>(gemm128x256<4>),
                      hipFuncAttributeMaxDynamicSharedMemorySize, SMEM_G);

  cvt_all<<<3072, 256, 0, stream>>>(qkv_w, proj_w, fc1_w, fc2_w,
                                    qkv_wb, proj_wb, fc1_wb, fc2_wb);
  bias_kernel<<<512, 256, 0, stream>>>(rpbt, biast);

  // LN1 + shift + window partition
  ln_kernel<true><<<32768, 256, 0, stream>>>(x, n1g, n1b, hln);

  // fused QKV -> head-major q/k/v (nwg = 1024*3 = 3072, %8==0)
  gemm128x256<4><<<3072, 512, SMEM_G, stream>>>(hln, qkv_wb, qkv_b, qbuf, kbuf, vbuf,
                                                nullptr, nullptr, nullptr, nullptr,
                                                MROWS, 768, 256, 3);

  // windowed attention (4 window-heads per 512-thread block)
  attn_kernel<<<4096, 512, 0, stream>>>(qbuf, kbuf, vbuf, biast, obuf);

  // proj + reverse-scatter + residual -> x2 fp32 in d_out, FUSED LN2 -> x2n (nwg=1024)
  gemm128x256<2><<<1024, 512, SMEM_P, stream>>>(obuf, proj_wb, proj_b, out, nullptr, nullptr,
                                                x, n2g, n2b, x2n, MROWS, 256, 256, 1);

  // MLP in 4 row-chunks (h2 chunk = 32768 x 1024 bf16 = 64MB, L3-resident)
  for (int c = 0; c < 4; ++c) {
    const bf16_t* xa = x2n + (size_t)c * 32768 * 256;
    gemm128x256<1><<<1024, 512, SMEM_G, stream>>>(xa, fc1_wb, fc1_b, h2, nullptr, nullptr,
                                                  nullptr, nullptr, nullptr, nullptr,
                                                  32768, 1024, 256, 4);
    gemm_bt<3><<<512, 256, 0, stream>>>(h2, fc2_wb, fc2_b, out + (size_t)c * 32768 * 256,
                                        32768, 256, 1024, 2);
  }
}

// Round 16
// 595.162 us; speedup vs baseline: 3.0897x; 1.1075x over previous
//
#include <hip/hip_runtime.h>
#include <hip/hip_bf16.h>
#include <stdint.h>

typedef __bf16 bf16_t;
typedef __bf16 bf16x8 __attribute__((ext_vector_type(8)));
typedef __bf16 bf16x4 __attribute__((ext_vector_type(4)));
typedef float f32x4 __attribute__((ext_vector_type(4)));

// Problem constants: B=32, H=W=64, C=256, heads=8, ws=8, ss=4
#define MROWS 131072   // B * 64 * 64 tokens (window layout rows)

__device__ __forceinline__ bf16_t to_bf16(float f) {
  __hip_bfloat16 h = __float2bfloat16(f);   // RNE
  return *reinterpret_cast<bf16_t*>(&h);
}

__device__ __forceinline__ f32x4 mfma16(bf16x8 a, bf16x8 b, f32x4 c) {
  return __builtin_amdgcn_mfma_f32_16x16x32_bf16(a, b, c, 0, 0, 0);
}

__device__ __forceinline__ void gload16(const void* g, void* l) {
  __builtin_amdgcn_global_load_lds(
      (const __attribute__((address_space(1))) void*)g,
      (__attribute__((address_space(3))) void*)l, 16, 0, 0);
}

// window-layout row m  ->  x row (shift+partition gather; reverse+unshift scatter)
__device__ __forceinline__ int map_row(int m) {
  int b   = m >> 12;
  int rem = m & 4095;
  int win = rem >> 6;
  int n   = rem & 63;
  int gh  = ((win >> 3) << 3) + (n >> 3);
  int gw  = ((win & 7) << 3) + (n & 7);
  int sh  = (gh + 4) & 63;
  int sw  = (gw + 4) & 63;
  return (b << 12) + (sh << 6) + sw;
}

// ---------------- fp32 -> bf16 weight convert (all 4 weight mats, one launch) ------
__global__ __launch_bounds__(256) void cvt_all(const float* __restrict__ qkv_w,
                                               const float* __restrict__ proj_w,
                                               const float* __restrict__ fc1_w,
                                               const float* __restrict__ fc2_w,
                                               bf16_t* __restrict__ qkv_o,
                                               bf16_t* __restrict__ proj_o,
                                               bf16_t* __restrict__ fc1_o,
                                               bf16_t* __restrict__ fc2_o) {
  int i = blockIdx.x * 256 + threadIdx.x;   // 0 .. 786431
  if (i < 196608)       qkv_o[i] = to_bf16(qkv_w[i]);
  else if (i < 262144)  proj_o[i - 196608] = to_bf16(proj_w[i - 196608]);
  else if (i < 524288)  fc1_o[i - 262144] = to_bf16(fc1_w[i - 262144]);
  else                  fc2_o[i - 524288] = to_bf16(fc2_w[i - 524288]);
}

// ---------------- bias table: bias[cls][h][n][m] = rpb(n,m,h) + mask(cls,n,m) ------
__global__ __launch_bounds__(256) void bias_kernel(const float* __restrict__ rpbt,
                                                   float* __restrict__ bias) {
  int idx = blockIdx.x * 256 + threadIdx.x;   // 0 .. 131071
  int m = idx & 63, n = (idx >> 6) & 63, h = (idx >> 12) & 7, c = idx >> 15;
  int yn = n >> 3, xn = n & 7, ym = m >> 3, xm = m & 7;
  float v = rpbt[((yn - ym + 7) * 15 + (xn - xm + 7)) * 8 + h];
  int rn = (c & 2) ? (yn < 4 ? 1 : 2) : 0;
  int cn = (c & 1) ? (xn < 4 ? 1 : 2) : 0;
  int rm = (c & 2) ? (ym < 4 ? 1 : 2) : 0;
  int cm = (c & 1) ? (xm < 4 ? 1 : 2) : 0;
  if (rn * 3 + cn != rm * 3 + cm) v -= 100.0f;
  bias[idx] = v;
}

// ---------------- LayerNorm (wave per row), row-permuted gather (LN1) ----------------
template <bool PERM>
__global__ __launch_bounds__(256) void ln_kernel(const float* __restrict__ xin,
                                                 const float* __restrict__ g,
                                                 const float* __restrict__ b,
                                                 bf16_t* __restrict__ out) {
  int row  = (blockIdx.x << 2) + (threadIdx.x >> 6);
  int lane = threadIdx.x & 63;
  int src  = PERM ? map_row(row) : row;
  float4 v = *reinterpret_cast<const float4*>(xin + (size_t)src * 256 + (lane << 2));
  float s = v.x + v.y + v.z + v.w;
#pragma unroll
  for (int d = 1; d < 64; d <<= 1) s += __shfl_xor(s, d);
  float mean = s * 0.00390625f;
  float ax = v.x - mean, ay = v.y - mean, az = v.z - mean, aw = v.w - mean;
  float s2 = ax * ax + ay * ay + az * az + aw * aw;
#pragma unroll
  for (int d = 1; d < 64; d <<= 1) s2 += __shfl_xor(s2, d);
  float rstd = rsqrtf(s2 * 0.00390625f + 1e-5f);
  float4 gv = *reinterpret_cast<const float4*>(g + (lane << 2));
  float4 bv = *reinterpret_cast<const float4*>(b + (lane << 2));
  bf16x4 o4;
  o4[0] = to_bf16(ax * rstd * gv.x + bv.x);
  o4[1] = to_bf16(ay * rstd * gv.y + bv.y);
  o4[2] = to_bf16(az * rstd * gv.z + bv.z);
  o4[3] = to_bf16(aw * rstd * gv.w + bv.w);
  *reinterpret_cast<bf16x4*>(out + (size_t)row * 256 + (lane << 2)) = o4;
}

// ======== 128(M)x256(N)-tile, 8 waves (2Mx4N), BK=32, 3-stage counted vmcnt ========
// Triple-buffered LDS 72KB -> 2 blocks/CU; steady-state s_waitcnt vmcnt(3);
// ONE barrier per K-tile (third buffer makes the extra buf-dead barrier unnecessary).
// T2 swizzle both-sides; T1 XCD swizzle; T5 setprio.
// EPI 1: GELU -> bf16 via LDS-bounce coalesced store (h2)
// EPI 2: proj: fp32 permuted store + resid + FUSED LN2 -> x2n
// EPI 4: qkv head-major split via LDS-bounce: wave w streams head w's 8KB block
template <int EPI>
__global__ __launch_bounds__(512, 4) void gemm128x256(const bf16_t* __restrict__ A,
                                                      const bf16_t* __restrict__ W,
                                                      const float* __restrict__ bias,
                                                      void* __restrict__ outp,
                                                      void* __restrict__ outp2,
                                                      void* __restrict__ outp3,
                                                      const float* __restrict__ resid,
                                                      const float* __restrict__ n2g,
                                                      const float* __restrict__ n2b,
                                                      bf16_t* __restrict__ x2n,
                                                      int M, int N, int K, int NBN) {
  extern __shared__ __align__(16) char smem[];
  bf16_t* As  = (bf16_t*)smem;              // [3][128*32]  (24 KB)
  bf16_t* Bs  = As + 3 * 4096;              // [3][256*32]  (48 KB)
  float*  lnS = (float*)(Bs + 3 * 8192);    // EPI2: [128][4]
  float*  lnQ = lnS + 512;                  // [128][4]
  float*  lnMR = lnQ + 512;                 // [128][2]
  const int tid  = threadIdx.x;
  const int lane = tid & 63, lo = lane & 15, hi = lane >> 4;
  const int wid  = tid >> 6, wm = wid >> 2, wn = wid & 3;
  const int cpx = gridDim.x >> 3;           // T1 XCD chunk swizzle
  const int wg  = (blockIdx.x & 7) * cpx + (blockIdx.x >> 3);
  const int bn = (wg % NBN) << 8, bm = (wg / NBN) << 7;
  f32x4 acc[4][4] = {};

  // STAGE one K-tile: 3 gloads/thread (A:1, B:2); source 16B-slot pre-swizzled (T2)
#define STG(buf, kt)                                                          \
  {                                                                           \
    int k0s = (kt) << 5;                                                      \
    {                                                                         \
      int ch = tid;                                                           \
      int row = ch >> 2, sl = ((ch & 3) ^ ((row >> 1) & 3)) << 3;             \
      gload16(A + (size_t)(bm + row) * K + k0s + sl,                          \
              &As[((buf) << 12) + (ch << 3)]);                                \
    }                                                                         \
    _Pragma("unroll") for (int l = 0; l < 2; ++l) {                           \
      int ch = (l << 9) + tid;                                                \
      int row = ch >> 2, sl = ((ch & 3) ^ ((row >> 1) & 3)) << 3;             \
      gload16(W + (size_t)(bn + row) * K + k0s + sl,                          \
              &Bs[((buf) << 13) + (ch << 3)]);                                \
    }                                                                         \
  }

  const int nt = K >> 5;                    // 8 (K=256)
  STG(0, 0);
  STG(1, 1);                                // 6 loads/thread outstanding

  int cb = 0;
  for (int t = 0; t < nt; ++t) {
    if (t + 1 < nt) { asm volatile("s_waitcnt vmcnt(3)" ::: "memory"); }
    else            { asm volatile("s_waitcnt vmcnt(0)" ::: "memory"); }
    __builtin_amdgcn_s_barrier();           // tile t ready; buf[t-1] reads done
    if (t + 2 < nt) {
      int sb = (cb == 0) ? 2 : cb - 1;      // (cb+2)%3
      STG(sb, t + 2);
    }
    const bf16_t* as = &As[cb << 12];
    const bf16_t* bs = &Bs[cb << 13];
    bf16x8 af[4], bfr[4];
#pragma unroll
    for (int i = 0; i < 4; ++i) {
      int ra = (wm << 6) + (i << 4) + lo;
      af[i] = *reinterpret_cast<const bf16x8*>(&as[ra * 32 + ((hi ^ ((ra >> 1) & 3)) << 3)]);
    }
#pragma unroll
    for (int j = 0; j < 4; ++j) {
      int rb = (wn << 6) + (j << 4) + lo;
      bfr[j] = *reinterpret_cast<const bf16x8*>(&bs[rb * 32 + ((hi ^ ((rb >> 1) & 3)) << 3)]);
    }
    __builtin_amdgcn_s_setprio(1);          // T5
#pragma unroll
    for (int i = 0; i < 4; ++i)
#pragma unroll
      for (int j = 0; j < 4; ++j)
        acc[i][j] = mfma16(af[i], bfr[j], acc[i][j]);
    __builtin_amdgcn_s_setprio(0);
    cb = (cb == 2) ? 0 : cb + 1;
  }
#undef STG

  float bv4[4];
#pragma unroll
  for (int nf = 0; nf < 4; ++nf) bv4[nf] = bias[bn + (wn << 6) + (nf << 4) + lo];

  if constexpr (EPI == 2) {
    // proj epilogue (BN = N = 256: full rows in-block): x2 = resid + o + b -> out
    // (permuted rows, fp32), then fused LN2 -> x2n bf16.
    float* o = (float*)outp;
    float gv[4], bnv[4];
#pragma unroll
    for (int nf = 0; nf < 4; ++nf) {
      int col = (wn << 6) + (nf << 4) + lo;
      gv[nf] = n2g[col]; bnv[nf] = n2b[col];
    }
#pragma unroll
    for (int mf = 0; mf < 4; ++mf)
#pragma unroll
      for (int r = 0; r < 4; ++r) {
        int rl = (wm << 6) + (mf << 4) + (hi << 2) + r;   // 0..127
        int xr = map_row(bm + rl);
        float s = 0.f, q = 0.f;
#pragma unroll
        for (int nf = 0; nf < 4; ++nf) {
          int col = (wn << 6) + (nf << 4) + lo;
          size_t idx = (size_t)xr * 256 + col;
          float v = resid[idx] + acc[mf][nf][r] + bv4[nf];
          acc[mf][nf][r] = v;
          o[idx] = v;
          s += v; q += v * v;
        }
#pragma unroll
        for (int d = 1; d < 16; d <<= 1) { s += __shfl_xor(s, d); q += __shfl_xor(q, d); }
        if (lo == 0) { lnS[(rl << 2) + wn] = s; lnQ[(rl << 2) + wn] = q; }
      }
    __syncthreads();
    if (tid < 128) {
      float s = lnS[tid << 2] + lnS[(tid << 2) + 1] + lnS[(tid << 2) + 2] + lnS[(tid << 2) + 3];
      float q = lnQ[tid << 2] + lnQ[(tid << 2) + 1] + lnQ[(tid << 2) + 2] + lnQ[(tid << 2) + 3];
      float mean = s * 0.00390625f;
      float var  = q * 0.00390625f - mean * mean;
      lnMR[tid << 1] = mean;
      lnMR[(tid << 1) + 1] = rsqrtf(var + 1e-5f);
    }
    __syncthreads();
#pragma unroll
    for (int mf = 0; mf < 4; ++mf)
#pragma unroll
      for (int r = 0; r < 4; ++r) {
        int rl = (wm << 6) + (mf << 4) + (hi << 2) + r;
        int xr = map_row(bm + rl);
        float mean = lnMR[rl << 1], rstd = lnMR[(rl << 1) + 1];
#pragma unroll
        for (int nf = 0; nf < 4; ++nf) {
          int col = (wn << 6) + (nf << 4) + lo;
          x2n[(size_t)xr * 256 + col] = to_bf16((acc[mf][nf][r] - mean) * rstd * gv[nf] + bnv[nf]);
        }
      }
  } else if constexpr (EPI == 4) {
    // QKV epilogue: LDS-bounce -> wave w streams head w's contiguous 8KB block.
    __syncthreads();                        // all waves done with As/Bs
    bf16_t* Os = (bf16_t*)smem;             // [128][264] bf16 (67.6 KB <= 72 KB)
#pragma unroll
    for (int mf = 0; mf < 4; ++mf)
#pragma unroll
      for (int r = 0; r < 4; ++r) {
        int rl = (wm << 6) + (mf << 4) + (hi << 2) + r;
#pragma unroll
        for (int nf = 0; nf < 4; ++nf) {
          int col = (wn << 6) + (nf << 4) + lo;
          Os[rl * 264 + col] = to_bf16(acc[mf][nf][r] + bv4[nf]);
        }
      }
    __syncthreads();
    {
      bf16_t* base = (bn == 0) ? (bf16_t*)outp
                   : (bn == 256) ? (bf16_t*)outp2 : (bf16_t*)outp3;
      bf16_t* dst = base + ((size_t)wid * MROWS + bm) * 32;   // head = wid
#pragma unroll
      for (int p = 0; p < 8; ++p) {
        int off = (p << 9) + (lane << 3);   // elem offset in 8KB head block
        int row = off >> 5, d0 = off & 31;  // row = p*16 + lane/4, d0 = (lane&3)*8
        bf16x8 v = *reinterpret_cast<const bf16x8*>(&Os[row * 264 + (wid << 5) + d0]);
        *reinterpret_cast<bf16x8*>(dst + off) = v;
      }
    }
  } else {
    // EPI 1: GELU -> bf16 via LDS-bounce, coalesced row-major store (h2)
    __syncthreads();                        // all waves done with As/Bs
    bf16_t* Os = (bf16_t*)smem;             // [128][264]
#pragma unroll
    for (int mf = 0; mf < 4; ++mf)
#pragma unroll
      for (int r = 0; r < 4; ++r) {
        int rl = (wm << 6) + (mf << 4) + (hi << 2) + r;
#pragma unroll
        for (int nf = 0; nf < 4; ++nf) {
          int col = (wn << 6) + (nf << 4) + lo;
          float v = acc[mf][nf][r] + bv4[nf];
          if constexpr (EPI == 1) v = 0.5f * v * (1.0f + erff(v * 0.70710678118654752f));
          Os[rl * 264 + col] = to_bf16(v);
        }
      }
    __syncthreads();
    {
      bf16_t* o = (bf16_t*)outp;
#pragma unroll
      for (int p = 0; p < 8; ++p) {
        int off = (p << 9) + (lane << 3);   // within wave's 16-row x 256-col slab
        int row = (wid << 4) + (off >> 8);  // wave w -> rows w*16..+16
        int col = off & 255;
        bf16x8 v = *reinterpret_cast<const bf16x8*>(&Os[row * 264 + col]);
        *reinterpret_cast<bf16x8*>(o + (size_t)(bm + row) * N + bn + col) = v;
      }
    }
  }
}

// ---------------- 128x128 bf16 GEMM, 3-stage counted-vmcnt (r8 proven) — FC2 ------
template <int EPI>
__global__ __launch_bounds__(256) void gemm_bt(const bf16_t* __restrict__ A,
                                               const bf16_t* __restrict__ W,
                                               const float* __restrict__ bias,
                                               void* __restrict__ outp,
                                               int M, int N, int K, int NBN) {
  __shared__ __align__(16) bf16_t As[3 * 128 * 32];
  __shared__ __align__(16) bf16_t Bs[3 * 128 * 32];
  const int tid  = threadIdx.x;
  const int lane = tid & 63, lo = lane & 15, hi = lane >> 4;
  const int wave = tid >> 6;
  const int cpx = gridDim.x >> 3;
  const int wg  = (blockIdx.x & 7) * cpx + (blockIdx.x >> 3);
  const int bn = (wg % NBN) << 7, bm = (wg / NBN) << 7;
  const int wr = (wave >> 1) << 6, wc = (wave & 1) << 6;
  f32x4 acc[4][4] = {};

#define STAGE(buf, kt)                                                         \
  {                                                                            \
    int k0s = (kt) << 5;                                                       \
    _Pragma("unroll") for (int it = 0; it < 2; ++it) {                         \
      int ch = (it << 8) + tid;                                                \
      int r = ch >> 2;                                                         \
      int kf = ((ch & 3) ^ ((r >> 1) & 3)) << 3;                               \
      gload16(A + (size_t)(bm + r) * K + k0s + kf, &As[((buf) << 12) + (ch << 3)]); \
      gload16(W + (size_t)(bn + r) * K + k0s + kf, &Bs[((buf) << 12) + (ch << 3)]); \
    }                                                                          \
  }

  const int nt = K >> 5;
  STAGE(0, 0);
  STAGE(1, 1);

  int cb = 0;
  for (int t = 0; t < nt; ++t) {
    if (t + 1 < nt) { asm volatile("s_waitcnt vmcnt(4)" ::: "memory"); }
    else            { asm volatile("s_waitcnt vmcnt(0)" ::: "memory"); }
    __builtin_amdgcn_s_barrier();
    if (t + 2 < nt) {
      int sb = (cb == 0) ? 2 : cb - 1;
      STAGE(sb, t + 2);
    }
    const bf16_t* as = &As[cb << 12];
    const bf16_t* bs = &Bs[cb << 12];
    bf16x8 af[4], bfr[4];
#pragma unroll
    for (int i = 0; i < 4; ++i) {
      int ra = wr + (i << 4) + lo;
      af[i] = *reinterpret_cast<const bf16x8*>(&as[ra * 32 + ((hi ^ ((ra >> 1) & 3)) << 3)]);
    }
#pragma unroll
    for (int j = 0; j < 4; ++j) {
      int rb = wc + (j << 4) + lo;
      bfr[j] = *reinterpret_cast<const bf16x8*>(&bs[rb * 32 + ((hi ^ ((rb >> 1) & 3)) << 3)]);
    }
    __builtin_amdgcn_s_setprio(1);
#pragma unroll
    for (int i = 0; i < 4; ++i)
#pragma unroll
      for (int j = 0; j < 4; ++j)
        acc[i][j] = mfma16(af[i], bfr[j], acc[i][j]);
    __builtin_amdgcn_s_setprio(0);
    cb = (cb == 2) ? 0 : cb + 1;
  }
#undef STAGE

  float bv[4];
#pragma unroll
  for (int j = 0; j < 4; ++j) bv[j] = bias[bn + wc + (j << 4) + lo];

#pragma unroll
  for (int i = 0; i < 4; ++i)
#pragma unroll
    for (int r = 0; r < 4; ++r) {
      int row = bm + wr + (i << 4) + (hi << 2) + r;
      float* o = (float*)outp;   // EPI 3 only
#pragma unroll
      for (int j = 0; j < 4; ++j) {
        int col = bn + wc + (j << 4) + lo;
        size_t idx = (size_t)row * 256 + col;
        o[idx] = o[idx] + acc[i][j][r] + bv[j];
      }
    }
}

// ---------------- windowed attention v2: wave PAIR per (window, head) ----------------
// 512 threads = 8 waves = 4 window-heads; pair (wh, sub) splits S/P/O rows by half.
__global__ __launch_bounds__(512) void attn_kernel(const bf16_t* __restrict__ qh,
                                                   const bf16_t* __restrict__ kh,
                                                   const bf16_t* __restrict__ vh,
                                                   const float* __restrict__ bias,
                                                   bf16_t* __restrict__ o) {
  __shared__ __align__(16) bf16_t Pl[4][64 * 72];
  __shared__ __align__(16) bf16_t Vt[4][32 * 72];
  const int tid = threadIdx.x;
  const int lane = tid & 63, lo = lane & 15, hi = lane >> 4;
  const int w = tid >> 6;                   // 0..7
  const int wh = w >> 1, sub = w & 1;       // window-head slot, row-half
  const int id = (blockIdx.x << 2) + wh;    // 0..16383
  const int win = id >> 3, h = id & 7;
  const size_t hb = ((size_t)h * MROWS + (size_t)win * 64) * 32;
  const bf16_t* qb = qh + hb;
  const bf16_t* kb = kh + hb;
  const bf16_t* vb = vh + hb;

  // stage V transposed: wave covers tokens m = sub*32 .. +31, both d-halves
  {
    int m  = (sub << 5) + (lane & 31);
    int dh = (lane >> 5) << 4;              // 0 | 16
    const bf16_t* vp = vb + (size_t)m * 32 + dh;
    bf16x8 v0 = *reinterpret_cast<const bf16x8*>(vp);
    bf16x8 v1 = *reinterpret_cast<const bf16x8*>(vp + 8);
#pragma unroll
    for (int e = 0; e < 8; ++e) {
      Vt[wh][(dh + e) * 72 + m]     = v0[e];
      Vt[wh][(dh + 8 + e) * 72 + m] = v1[e];
    }
  }

  // QK^T: rows n = sub*32 .. +31 (2 frags), all 64 K rows (4 frags)
  bf16x8 qa[2], ka[4];
#pragma unroll
  for (int il = 0; il < 2; ++il)
    qa[il] = *reinterpret_cast<const bf16x8*>(qb + ((sub << 5) + (il << 4) + lo) * 32 + (hi << 3));
#pragma unroll
  for (int j = 0; j < 4; ++j)
    ka[j] = *reinterpret_cast<const bf16x8*>(kb + ((j << 4) + lo) * 32 + (hi << 3));
  f32x4 s4[2][4] = {};
#pragma unroll
  for (int il = 0; il < 2; ++il)
#pragma unroll
    for (int j = 0; j < 4; ++j) s4[il][j] = mfma16(qa[il], ka[j], s4[il][j]);

  const int whw = (win & 63) >> 3, www = win & 7;
  const int cls = ((whw == 7) ? 2 : 0) + ((www == 7) ? 1 : 0);
  const float* bb = bias + ((size_t)cls * 8 + h) * 4096;
  const float scale = 0.17677669529663687f;  // 1/sqrt(32)

  float pinv[2][4];
#pragma unroll
  for (int il = 0; il < 2; ++il) {
#pragma unroll
    for (int r = 0; r < 4; ++r) {
      int n = (sub << 5) + (il << 4) + (hi << 2) + r;
      const float* brow = bb + n * 64 + lo;
      float vals[4], mx = -1e30f;
#pragma unroll
      for (int j = 0; j < 4; ++j) {
        float val = s4[il][j][r] * scale + brow[j << 4];
        vals[j] = val;
        mx = fmaxf(mx, val);
      }
#pragma unroll
      for (int d = 1; d < 16; d <<= 1) mx = fmaxf(mx, __shfl_xor(mx, d));
      float sum = 0.0f;
#pragma unroll
      for (int j = 0; j < 4; ++j) {
        float p = __expf(vals[j] - mx);
        sum += p;
        Pl[wh][n * 72 + (j << 4) + lo] = to_bf16(p);
      }
#pragma unroll
      for (int d = 1; d < 16; d <<= 1) sum += __shfl_xor(sum, d);
      pinv[il][r] = 1.0f / sum;
    }
  }

  __syncthreads();   // Vt + Pl complete (pair + block)

  // PV: O[own 32, 32] = P[own 32, 64] @ V[64, 32]
  f32x4 oa[2][2] = {};
#pragma unroll
  for (int kt = 0; kt < 2; ++kt) {
    bf16x8 pa[2], va[2];
#pragma unroll
    for (int il = 0; il < 2; ++il)
      pa[il] = *reinterpret_cast<const bf16x8*>(&Pl[wh][((sub << 5) + (il << 4) + lo) * 72 + (kt << 5) + (hi << 3)]);
#pragma unroll
    for (int dt = 0; dt < 2; ++dt)
      va[dt] = *reinterpret_cast<const bf16x8*>(&Vt[wh][((dt << 4) + lo) * 72 + (kt << 5) + (hi << 3)]);
#pragma unroll
    for (int il = 0; il < 2; ++il)
#pragma unroll
      for (int dt = 0; dt < 2; ++dt) oa[il][dt] = mfma16(pa[il], va[dt], oa[il][dt]);
  }

  bf16_t* ob = o + (size_t)win * (64 * 256) + h * 32;
#pragma unroll
  for (int il = 0; il < 2; ++il)
#pragma unroll
    for (int r = 0; r < 4; ++r) {
      int n = (sub << 5) + (il << 4) + (hi << 2) + r;
      float piv = pinv[il][r];
#pragma unroll
      for (int dt = 0; dt < 2; ++dt)
        ob[(size_t)n * 256 + (dt << 4) + lo] = to_bf16(oa[il][dt][r] * piv);
    }
}

// ---------------- launch ----------------
extern "C" void kernel_launch(void* const* d_in, const int* in_sizes, int n_in,
                              void* d_out, int out_size, void* d_ws, size_t ws_size,
                              hipStream_t stream) {
  const float* x      = (const float*)d_in[0];
  const float* n1g    = (const float*)d_in[1];
  const float* n1b    = (const float*)d_in[2];
  const float* qkv_w  = (const float*)d_in[3];
  const float* qkv_b  = (const float*)d_in[4];
  const float* rpbt   = (const float*)d_in[5];
  const float* proj_w = (const float*)d_in[6];
  const float* proj_b = (const float*)d_in[7];
  const float* n2g    = (const float*)d_in[8];
  const float* n2b    = (const float*)d_in[9];
  const float* fc1_w  = (const float*)d_in[10];
  const float* fc1_b  = (const float*)d_in[11];
  const float* fc2_w  = (const float*)d_in[12];
  const float* fc2_b  = (const float*)d_in[13];
  float* out = (float*)d_out;
  char*  ws  = (char*)d_ws;

  // ws: [0,64Mi) hln -> obuf -> h2 chunk | [64Mi,128Mi) qbuf -> x2n | [128Mi..] weights+bias
  // d_out doubles as scratch: k,v bf16 (head-major) until proj, then x2/out fp32.
  const size_t MB64 = 67108864;
  bf16_t* hln  = (bf16_t*)(ws);
  bf16_t* obuf = (bf16_t*)(ws);
  bf16_t* h2   = (bf16_t*)(ws);
  bf16_t* qbuf = (bf16_t*)(ws + MB64);
  bf16_t* x2n  = (bf16_t*)(ws + MB64);
  bf16_t* wb   = (bf16_t*)(ws + 2 * MB64);
  bf16_t* qkv_wb  = wb;                   // 196608 el
  bf16_t* proj_wb = qkv_wb + 196608;      // 65536
  bf16_t* fc1_wb  = proj_wb + 65536;      // 262144
  bf16_t* fc2_wb  = fc1_wb + 262144;      // 262144
  float*  biast   = (float*)(fc2_wb + 262144);  // 131072 f32 = 512KB
  bf16_t* kbuf = (bf16_t*)d_out;          // 33554432 el (64MiB)
  bf16_t* vbuf = kbuf + 33554432;

  const int SMEM_G = 73728;               // 3x(As 8KB + Bs 16KB)
  const int SMEM_P = 78848;               // + LN scratch (EPI2)
  hipFuncSetAttribute(reinterpret_cast<const void*>(gemm128x256<1>),
                      hipFuncAttributeMaxDynamicSharedMemorySize, SMEM_G);
  hipFuncSetAttribute(reinterpret_cast<const void*>(gemm128x256<2>),
                      hipFuncAttributeMaxDynamicSharedMemorySize, SMEM_P);
  hipFuncSetAttribute(reinterpret_cast<const void*>(gemm128x256<4>),
                      hipFuncAttributeMaxDynamicSharedMemorySize, SMEM_G);

  cvt_all<<<3072, 256, 0, stream>>>(qkv_w, proj_w, fc1_w, fc2_w,
                                    qkv_wb, proj_wb, fc1_wb, fc2_wb);
  bias_kernel<<<512, 256, 0, stream>>>(rpbt, biast);

  // LN1 + shift + window partition
  ln_kernel<true><<<32768, 256, 0, stream>>>(x, n1g, n1b, hln);

  // fused QKV -> head-major q/k/v (nwg = 1024*3 = 3072, %8==0)
  gemm128x256<4><<<3072, 512, SMEM_G, stream>>>(hln, qkv_wb, qkv_b, qbuf, kbuf, vbuf,
                                                nullptr, nullptr, nullptr, nullptr,
                                                MROWS, 768, 256, 3);

  // windowed attention (4 window-heads per 512-thread block)
  attn_kernel<<<4096, 512, 0, stream>>>(qbuf, kbuf, vbuf, biast, obuf);

  // proj + reverse-scatter + residual -> x2 fp32 in d_out, FUSED LN2 -> x2n (nwg=1024)
  gemm128x256<2><<<1024, 512, SMEM_P, stream>>>(obuf, proj_wb, proj_b, out, nullptr, nullptr,
                                                x, n2g, n2b, x2n, MROWS, 256, 256, 1);

  // MLP in 4 row-chunks (h2 chunk = 32768 x 1024 bf16 = 64MB, L3-resident)
  for (int c = 0; c < 4; ++c) {
    const bf16_t* xa = x2n + (size_t)c * 32768 * 256;
    gemm128x256<1><<<1024, 512, SMEM_G, stream>>>(xa, fc1_wb, fc1_b, h2, nullptr, nullptr,
                                                  nullptr, nullptr, nullptr, nullptr,
                                                  32768, 1024, 256, 4);
    gemm_bt<3><<<512, 256, 0, stream>>>(h2, fc2_wb, fc2_b, out + (size_t)c * 32768 * 256,
                                        32768, 256, 1024, 2);
  }
}

// Round 17
// 584.118 us; speedup vs baseline: 3.1481x; 1.0189x over previous
//
#include <hip/hip_runtime.h>
#include <hip/hip_bf16.h>
#include <stdint.h>

typedef __bf16 bf16_t;
typedef __bf16 bf16x8 __attribute__((ext_vector_type(8)));
typedef __bf16 bf16x4 __attribute__((ext_vector_type(4)));
typedef float f32x4 __attribute__((ext_vector_type(4)));

// Problem constants: B=32, H=W=64, C=256, heads=8, ws=8, ss=4
#define MROWS 131072   // B * 64 * 64 tokens (window layout rows)

__device__ __forceinline__ bf16_t to_bf16(float f) {
  __hip_bfloat16 h = __float2bfloat16(f);   // RNE
  return *reinterpret_cast<bf16_t*>(&h);
}

__device__ __forceinline__ f32x4 mfma16(bf16x8 a, bf16x8 b, f32x4 c) {
  return __builtin_amdgcn_mfma_f32_16x16x32_bf16(a, b, c, 0, 0, 0);
}

__device__ __forceinline__ void gload16(const void* g, void* l) {
  __builtin_amdgcn_global_load_lds(
      (const __attribute__((address_space(1))) void*)g,
      (__attribute__((address_space(3))) void*)l, 16, 0, 0);
}

// window-layout row m  ->  x row (shift+partition gather; reverse+unshift scatter)
__device__ __forceinline__ int map_row(int m) {
  int b   = m >> 12;
  int rem = m & 4095;
  int win = rem >> 6;
  int n   = rem & 63;
  int gh  = ((win >> 3) << 3) + (n >> 3);
  int gw  = ((win & 7) << 3) + (n & 7);
  int sh  = (gh + 4) & 63;
  int sw  = (gw + 4) & 63;
  return (b << 12) + (sh << 6) + sw;
}

// ---------------- prep: fp32->bf16 weight convert + rpb/mask bias table, one launch ----
// blocks [0,3072): weight convert (786432 el). blocks [3072,3584): bias table.
__global__ __launch_bounds__(256) void prep_kernel(const float* __restrict__ qkv_w,
                                                   const float* __restrict__ proj_w,
                                                   const float* __restrict__ fc1_w,
                                                   const float* __restrict__ fc2_w,
                                                   const float* __restrict__ rpbt,
                                                   bf16_t* __restrict__ qkv_o,
                                                   bf16_t* __restrict__ proj_o,
                                                   bf16_t* __restrict__ fc1_o,
                                                   bf16_t* __restrict__ fc2_o,
                                                   float* __restrict__ bias) {
  if (blockIdx.x < 3072) {
    int i = blockIdx.x * 256 + threadIdx.x;   // 0 .. 786431
    if (i < 196608)       qkv_o[i] = to_bf16(qkv_w[i]);
    else if (i < 262144)  proj_o[i - 196608] = to_bf16(proj_w[i - 196608]);
    else if (i < 524288)  fc1_o[i - 262144] = to_bf16(fc1_w[i - 262144]);
    else                  fc2_o[i - 524288] = to_bf16(fc2_w[i - 524288]);
  } else {
    int idx = (blockIdx.x - 3072) * 256 + threadIdx.x;   // 0 .. 131071
    int m = idx & 63, n = (idx >> 6) & 63, h = (idx >> 12) & 7, c = idx >> 15;
    int yn = n >> 3, xn = n & 7, ym = m >> 3, xm = m & 7;
    float v = rpbt[((yn - ym + 7) * 15 + (xn - xm + 7)) * 8 + h];
    int rn = (c & 2) ? (yn < 4 ? 1 : 2) : 0;
    int cn = (c & 1) ? (xn < 4 ? 1 : 2) : 0;
    int rm = (c & 2) ? (ym < 4 ? 1 : 2) : 0;
    int cm = (c & 1) ? (xm < 4 ? 1 : 2) : 0;
    if (rn * 3 + cn != rm * 3 + cm) v -= 100.0f;
    bias[idx] = v;
  }
}

// ---------------- LayerNorm (wave per row), row-permuted gather (LN1) ----------------
template <bool PERM>
__global__ __launch_bounds__(256) void ln_kernel(const float* __restrict__ xin,
                                                 const float* __restrict__ g,
                                                 const float* __restrict__ b,
                                                 bf16_t* __restrict__ out) {
  int row  = (blockIdx.x << 2) + (threadIdx.x >> 6);
  int lane = threadIdx.x & 63;
  int src  = PERM ? map_row(row) : row;
  float4 v = *reinterpret_cast<const float4*>(xin + (size_t)src * 256 + (lane << 2));
  float s = v.x + v.y + v.z + v.w;
#pragma unroll
  for (int d = 1; d < 64; d <<= 1) s += __shfl_xor(s, d);
  float mean = s * 0.00390625f;
  float ax = v.x - mean, ay = v.y - mean, az = v.z - mean, aw = v.w - mean;
  float s2 = ax * ax + ay * ay + az * az + aw * aw;
#pragma unroll
  for (int d = 1; d < 64; d <<= 1) s2 += __shfl_xor(s2, d);
  float rstd = rsqrtf(s2 * 0.00390625f + 1e-5f);
  float4 gv = *reinterpret_cast<const float4*>(g + (lane << 2));
  float4 bv = *reinterpret_cast<const float4*>(b + (lane << 2));
  bf16x4 o4;
  o4[0] = to_bf16(ax * rstd * gv.x + bv.x);
  o4[1] = to_bf16(ay * rstd * gv.y + bv.y);
  o4[2] = to_bf16(az * rstd * gv.z + bv.z);
  o4[3] = to_bf16(aw * rstd * gv.w + bv.w);
  *reinterpret_cast<bf16x4*>(out + (size_t)row * 256 + (lane << 2)) = o4;
}

// ======== 128(M)x256(N)-tile, 8 waves (2Mx4N), BK=32, 3-stage counted vmcnt ========
// Triple-buffered LDS 72KB -> 2 blocks/CU; steady-state s_waitcnt vmcnt(3);
// ONE barrier per K-tile (third buffer makes the extra buf-dead barrier unnecessary).
// T2 swizzle both-sides; T1 XCD swizzle; T5 setprio.
// EPI 1: GELU -> bf16 via LDS-bounce coalesced store (h2)
// EPI 2: proj: fp32 permuted store + resid + FUSED LN2 -> x2n
// EPI 4: qkv head-major split via LDS-bounce: wave w streams head w's 8KB block
template <int EPI>
__global__ __launch_bounds__(512, 4) void gemm128x256(const bf16_t* __restrict__ A,
                                                      const bf16_t* __restrict__ W,
                                                      const float* __restrict__ bias,
                                                      void* __restrict__ outp,
                                                      void* __restrict__ outp2,
                                                      void* __restrict__ outp3,
                                                      const float* __restrict__ resid,
                                                      const float* __restrict__ n2g,
                                                      const float* __restrict__ n2b,
                                                      bf16_t* __restrict__ x2n,
                                                      int M, int N, int K, int NBN) {
  extern __shared__ __align__(16) char smem[];
  bf16_t* As  = (bf16_t*)smem;              // [3][128*32]  (24 KB)
  bf16_t* Bs  = As + 3 * 4096;              // [3][256*32]  (48 KB)
  float*  lnS = (float*)(Bs + 3 * 8192);    // EPI2: [128][4]
  float*  lnQ = lnS + 512;                  // [128][4]
  float*  lnMR = lnQ + 512;                 // [128][2]
  const int tid  = threadIdx.x;
  const int lane = tid & 63, lo = lane & 15, hi = lane >> 4;
  const int wid  = tid >> 6, wm = wid >> 2, wn = wid & 3;
  const int cpx = gridDim.x >> 3;           // T1 XCD chunk swizzle
  const int wg  = (blockIdx.x & 7) * cpx + (blockIdx.x >> 3);
  const int bn = (wg % NBN) << 8, bm = (wg / NBN) << 7;
  f32x4 acc[4][4] = {};

  // STAGE one K-tile: 3 gloads/thread (A:1, B:2); source 16B-slot pre-swizzled (T2)
#define STG(buf, kt)                                                          \
  {                                                                           \
    int k0s = (kt) << 5;                                                      \
    {                                                                         \
      int ch = tid;                                                           \
      int row = ch >> 2, sl = ((ch & 3) ^ ((row >> 1) & 3)) << 3;             \
      gload16(A + (size_t)(bm + row) * K + k0s + sl,                          \
              &As[((buf) << 12) + (ch << 3)]);                                \
    }                                                                         \
    _Pragma("unroll") for (int l = 0; l < 2; ++l) {                           \
      int ch = (l << 9) + tid;                                                \
      int row = ch >> 2, sl = ((ch & 3) ^ ((row >> 1) & 3)) << 3;             \
      gload16(W + (size_t)(bn + row) * K + k0s + sl,                          \
              &Bs[((buf) << 13) + (ch << 3)]);                                \
    }                                                                         \
  }

  const int nt = K >> 5;                    // 8 (K=256)
  STG(0, 0);
  STG(1, 1);                                // 6 loads/thread outstanding

  int cb = 0;
  for (int t = 0; t < nt; ++t) {
    if (t + 1 < nt) { asm volatile("s_waitcnt vmcnt(3)" ::: "memory"); }
    else            { asm volatile("s_waitcnt vmcnt(0)" ::: "memory"); }
    __builtin_amdgcn_s_barrier();           // tile t ready; buf[t-1] reads done
    if (t + 2 < nt) {
      int sb = (cb == 0) ? 2 : cb - 1;      // (cb+2)%3
      STG(sb, t + 2);
    }
    const bf16_t* as = &As[cb << 12];
    const bf16_t* bs = &Bs[cb << 13];
    bf16x8 af[4], bfr[4];
#pragma unroll
    for (int i = 0; i < 4; ++i) {
      int ra = (wm << 6) + (i << 4) + lo;
      af[i] = *reinterpret_cast<const bf16x8*>(&as[ra * 32 + ((hi ^ ((ra >> 1) & 3)) << 3)]);
    }
#pragma unroll
    for (int j = 0; j < 4; ++j) {
      int rb = (wn << 6) + (j << 4) + lo;
      bfr[j] = *reinterpret_cast<const bf16x8*>(&bs[rb * 32 + ((hi ^ ((rb >> 1) & 3)) << 3)]);
    }
    __builtin_amdgcn_s_setprio(1);          // T5
#pragma unroll
    for (int i = 0; i < 4; ++i)
#pragma unroll
      for (int j = 0; j < 4; ++j)
        acc[i][j] = mfma16(af[i], bfr[j], acc[i][j]);
    __builtin_amdgcn_s_setprio(0);
    cb = (cb == 2) ? 0 : cb + 1;
  }
#undef STG

  float bv4[4];
#pragma unroll
  for (int nf = 0; nf < 4; ++nf) bv4[nf] = bias[bn + (wn << 6) + (nf << 4) + lo];

  if constexpr (EPI == 2) {
    // proj epilogue (BN = N = 256: full rows in-block): x2 = resid + o + b -> out
    // (permuted rows, fp32), then fused LN2 -> x2n bf16.
    float* o = (float*)outp;
    float gv[4], bnv[4];
#pragma unroll
    for (int nf = 0; nf < 4; ++nf) {
      int col = (wn << 6) + (nf << 4) + lo;
      gv[nf] = n2g[col]; bnv[nf] = n2b[col];
    }
#pragma unroll
    for (int mf = 0; mf < 4; ++mf)
#pragma unroll
      for (int r = 0; r < 4; ++r) {
        int rl = (wm << 6) + (mf << 4) + (hi << 2) + r;   // 0..127
        int xr = map_row(bm + rl);
        float s = 0.f, q = 0.f;
#pragma unroll
        for (int nf = 0; nf < 4; ++nf) {
          int col = (wn << 6) + (nf << 4) + lo;
          size_t idx = (size_t)xr * 256 + col;
          float v = resid[idx] + acc[mf][nf][r] + bv4[nf];
          acc[mf][nf][r] = v;
          o[idx] = v;
          s += v; q += v * v;
        }
#pragma unroll
        for (int d = 1; d < 16; d <<= 1) { s += __shfl_xor(s, d); q += __shfl_xor(q, d); }
        if (lo == 0) { lnS[(rl << 2) + wn] = s; lnQ[(rl << 2) + wn] = q; }
      }
    __syncthreads();
    if (tid < 128) {
      float s = lnS[tid << 2] + lnS[(tid << 2) + 1] + lnS[(tid << 2) + 2] + lnS[(tid << 2) + 3];
      float q = lnQ[tid << 2] + lnQ[(tid << 2) + 1] + lnQ[(tid << 2) + 2] + lnQ[(tid << 2) + 3];
      float mean = s * 0.00390625f;
      float var  = q * 0.00390625f - mean * mean;
      lnMR[tid << 1] = mean;
      lnMR[(tid << 1) + 1] = rsqrtf(var + 1e-5f);
    }
    __syncthreads();
#pragma unroll
    for (int mf = 0; mf < 4; ++mf)
#pragma unroll
      for (int r = 0; r < 4; ++r) {
        int rl = (wm << 6) + (mf << 4) + (hi << 2) + r;
        int xr = map_row(bm + rl);
        float mean = lnMR[rl << 1], rstd = lnMR[(rl << 1) + 1];
#pragma unroll
        for (int nf = 0; nf < 4; ++nf) {
          int col = (wn << 6) + (nf << 4) + lo;
          x2n[(size_t)xr * 256 + col] = to_bf16((acc[mf][nf][r] - mean) * rstd * gv[nf] + bnv[nf]);
        }
      }
  } else if constexpr (EPI == 4) {
    // QKV epilogue: LDS-bounce -> wave w streams head w's contiguous 8KB block.
    __syncthreads();                        // all waves done with As/Bs
    bf16_t* Os = (bf16_t*)smem;             // [128][264] bf16 (67.6 KB <= 72 KB)
#pragma unroll
    for (int mf = 0; mf < 4; ++mf)
#pragma unroll
      for (int r = 0; r < 4; ++r) {
        int rl = (wm << 6) + (mf << 4) + (hi << 2) + r;
#pragma unroll
        for (int nf = 0; nf < 4; ++nf) {
          int col = (wn << 6) + (nf << 4) + lo;
          Os[rl * 264 + col] = to_bf16(acc[mf][nf][r] + bv4[nf]);
        }
      }
    __syncthreads();
    {
      bf16_t* base = (bn == 0) ? (bf16_t*)outp
                   : (bn == 256) ? (bf16_t*)outp2 : (bf16_t*)outp3;
      bf16_t* dst = base + ((size_t)wid * MROWS + bm) * 32;   // head = wid
#pragma unroll
      for (int p = 0; p < 8; ++p) {
        int off = (p << 9) + (lane << 3);   // elem offset in 8KB head block
        int row = off >> 5, d0 = off & 31;  // row = p*16 + lane/4, d0 = (lane&3)*8
        bf16x8 v = *reinterpret_cast<const bf16x8*>(&Os[row * 264 + (wid << 5) + d0]);
        *reinterpret_cast<bf16x8*>(dst + off) = v;
      }
    }
  } else {
    // EPI 1: GELU -> bf16 via LDS-bounce, coalesced row-major store (h2)
    __syncthreads();                        // all waves done with As/Bs
    bf16_t* Os = (bf16_t*)smem;             // [128][264]
#pragma unroll
    for (int mf = 0; mf < 4; ++mf)
#pragma unroll
      for (int r = 0; r < 4; ++r) {
        int rl = (wm << 6) + (mf << 4) + (hi << 2) + r;
#pragma unroll
        for (int nf = 0; nf < 4; ++nf) {
          int col = (wn << 6) + (nf << 4) + lo;
          float v = acc[mf][nf][r] + bv4[nf];
          if constexpr (EPI == 1) v = 0.5f * v * (1.0f + erff(v * 0.70710678118654752f));
          Os[rl * 264 + col] = to_bf16(v);
        }
      }
    __syncthreads();
    {
      bf16_t* o = (bf16_t*)outp;
#pragma unroll
      for (int p = 0; p < 8; ++p) {
        int off = (p << 9) + (lane << 3);   // within wave's 16-row x 256-col slab
        int row = (wid << 4) + (off >> 8);  // wave w -> rows w*16..+16
        int col = off & 255;
        bf16x8 v = *reinterpret_cast<const bf16x8*>(&Os[row * 264 + col]);
        *reinterpret_cast<bf16x8*>(o + (size_t)(bm + row) * N + bn + col) = v;
      }
    }
  }
}

// ---------------- 128x128 bf16 GEMM, 3-stage counted-vmcnt (r8 proven) — FC2 ------
template <int EPI>
__global__ __launch_bounds__(256) void gemm_bt(const bf16_t* __restrict__ A,
                                               const bf16_t* __restrict__ W,
                                               const float* __restrict__ bias,
                                               void* __restrict__ outp,
                                               int M, int N, int K, int NBN) {
  __shared__ __align__(16) bf16_t As[3 * 128 * 32];
  __shared__ __align__(16) bf16_t Bs[3 * 128 * 32];
  const int tid  = threadIdx.x;
  const int lane = tid & 63, lo = lane & 15, hi = lane >> 4;
  const int wave = tid >> 6;
  const int cpx = gridDim.x >> 3;
  const int wg  = (blockIdx.x & 7) * cpx + (blockIdx.x >> 3);
  const int bn = (wg % NBN) << 7, bm = (wg / NBN) << 7;
  const int wr = (wave >> 1) << 6, wc = (wave & 1) << 6;
  f32x4 acc[4][4] = {};

#define STAGE(buf, kt)                                                         \
  {                                                                            \
    int k0s = (kt) << 5;                                                       \
    _Pragma("unroll") for (int it = 0; it < 2; ++it) {                         \
      int ch = (it << 8) + tid;                                                \
      int r = ch >> 2;                                                         \
      int kf = ((ch & 3) ^ ((r >> 1) & 3)) << 3;                               \
      gload16(A + (size_t)(bm + r) * K + k0s + kf, &As[((buf) << 12) + (ch << 3)]); \
      gload16(W + (size_t)(bn + r) * K + k0s + kf, &Bs[((buf) << 12) + (ch << 3)]); \
    }                                                                          \
  }

  const int nt = K >> 5;
  STAGE(0, 0);
  STAGE(1, 1);

  int cb = 0;
  for (int t = 0; t < nt; ++t) {
    if (t + 1 < nt) { asm volatile("s_waitcnt vmcnt(4)" ::: "memory"); }
    else            { asm volatile("s_waitcnt vmcnt(0)" ::: "memory"); }
    __builtin_amdgcn_s_barrier();
    if (t + 2 < nt) {
      int sb = (cb == 0) ? 2 : cb - 1;
      STAGE(sb, t + 2);
    }
    const bf16_t* as = &As[cb << 12];
    const bf16_t* bs = &Bs[cb << 12];
    bf16x8 af[4], bfr[4];
#pragma unroll
    for (int i = 0; i < 4; ++i) {
      int ra = wr + (i << 4) + lo;
      af[i] = *reinterpret_cast<const bf16x8*>(&as[ra * 32 + ((hi ^ ((ra >> 1) & 3)) << 3)]);
    }
#pragma unroll
    for (int j = 0; j < 4; ++j) {
      int rb = wc + (j << 4) + lo;
      bfr[j] = *reinterpret_cast<const bf16x8*>(&bs[rb * 32 + ((hi ^ ((rb >> 1) & 3)) << 3)]);
    }
    __builtin_amdgcn_s_setprio(1);
#pragma unroll
    for (int i = 0; i < 4; ++i)
#pragma unroll
      for (int j = 0; j < 4; ++j)
        acc[i][j] = mfma16(af[i], bfr[j], acc[i][j]);
    __builtin_amdgcn_s_setprio(0);
    cb = (cb == 2) ? 0 : cb + 1;
  }
#undef STAGE

  float bv[4];
#pragma unroll
  for (int j = 0; j < 4; ++j) bv[j] = bias[bn + wc + (j << 4) + lo];

#pragma unroll
  for (int i = 0; i < 4; ++i)
#pragma unroll
    for (int r = 0; r < 4; ++r) {
      int row = bm + wr + (i << 4) + (hi << 2) + r;
      float* o = (float*)outp;   // EPI 3 only
#pragma unroll
      for (int j = 0; j < 4; ++j) {
        int col = bn + wc + (j << 4) + lo;
        size_t idx = (size_t)row * 256 + col;
        o[idx] = o[idx] + acc[i][j][r] + bv[j];
      }
    }
}

// ---------------- windowed attention v2: wave PAIR per (window, head) ----------------
// 512 threads = 8 waves = 4 window-heads; pair (wh, sub) splits S/P/O rows by half.
__global__ __launch_bounds__(512) void attn_kernel(const bf16_t* __restrict__ qh,
                                                   const bf16_t* __restrict__ kh,
                                                   const bf16_t* __restrict__ vh,
                                                   const float* __restrict__ bias,
                                                   bf16_t* __restrict__ o) {
  __shared__ __align__(16) bf16_t Pl[4][64 * 72];
  __shared__ __align__(16) bf16_t Vt[4][32 * 72];
  const int tid = threadIdx.x;
  const int lane = tid & 63, lo = lane & 15, hi = lane >> 4;
  const int w = tid >> 6;                   // 0..7
  const int wh = w >> 1, sub = w & 1;       // window-head slot, row-half
  const int id = (blockIdx.x << 2) + wh;    // 0..16383
  const int win = id >> 3, h = id & 7;
  const size_t hb = ((size_t)h * MROWS + (size_t)win * 64) * 32;
  const bf16_t* qb = qh + hb;
  const bf16_t* kb = kh + hb;
  const bf16_t* vb = vh + hb;

  // stage V transposed: wave covers tokens m = sub*32 .. +31, both d-halves
  {
    int m  = (sub << 5) + (lane & 31);
    int dh = (lane >> 5) << 4;              // 0 | 16
    const bf16_t* vp = vb + (size_t)m * 32 + dh;
    bf16x8 v0 = *reinterpret_cast<const bf16x8*>(vp);
    bf16x8 v1 = *reinterpret_cast<const bf16x8*>(vp + 8);
#pragma unroll
    for (int e = 0; e < 8; ++e) {
      Vt[wh][(dh + e) * 72 + m]     = v0[e];
      Vt[wh][(dh + 8 + e) * 72 + m] = v1[e];
    }
  }

  // QK^T: rows n = sub*32 .. +31 (2 frags), all 64 K rows (4 frags)
  bf16x8 qa[2], ka[4];
#pragma unroll
  for (int il = 0; il < 2; ++il)
    qa[il] = *reinterpret_cast<const bf16x8*>(qb + ((sub << 5) + (il << 4) + lo) * 32 + (hi << 3));
#pragma unroll
  for (int j = 0; j < 4; ++j)
    ka[j] = *reinterpret_cast<const bf16x8*>(kb + ((j << 4) + lo) * 32 + (hi << 3));
  f32x4 s4[2][4] = {};
#pragma unroll
  for (int il = 0; il < 2; ++il)
#pragma unroll
    for (int j = 0; j < 4; ++j) s4[il][j] = mfma16(qa[il], ka[j], s4[il][j]);

  const int whw = (win & 63) >> 3, www = win & 7;
  const int cls = ((whw == 7) ? 2 : 0) + ((www == 7) ? 1 : 0);
  const float* bb = bias + ((size_t)cls * 8 + h) * 4096;
  const float scale = 0.17677669529663687f;  // 1/sqrt(32)

  float pinv[2][4];
#pragma unroll
  for (int il = 0; il < 2; ++il) {
#pragma unroll
    for (int r = 0; r < 4; ++r) {
      int n = (sub << 5) + (il << 4) + (hi << 2) + r;
      const float* brow = bb + n * 64 + lo;
      float vals[4], mx = -1e30f;
#pragma unroll
      for (int j = 0; j < 4; ++j) {
        float val = s4[il][j][r] * scale + brow[j << 4];
        vals[j] = val;
        mx = fmaxf(mx, val);
      }
#pragma unroll
      for (int d = 1; d < 16; d <<= 1) mx = fmaxf(mx, __shfl_xor(mx, d));
      float sum = 0.0f;
#pragma unroll
      for (int j = 0; j < 4; ++j) {
        float p = __expf(vals[j] - mx);
        sum += p;
        Pl[wh][n * 72 + (j << 4) + lo] = to_bf16(p);
      }
#pragma unroll
      for (int d = 1; d < 16; d <<= 1) sum += __shfl_xor(sum, d);
      pinv[il][r] = 1.0f / sum;
    }
  }

  __syncthreads();   // Vt + Pl complete (pair + block)

  // PV: O[own 32, 32] = P[own 32, 64] @ V[64, 32]
  f32x4 oa[2][2] = {};
#pragma unroll
  for (int kt = 0; kt < 2; ++kt) {
    bf16x8 pa[2], va[2];
#pragma unroll
    for (int il = 0; il < 2; ++il)
      pa[il] = *reinterpret_cast<const bf16x8*>(&Pl[wh][((sub << 5) + (il << 4) + lo) * 72 + (kt << 5) + (hi << 3)]);
#pragma unroll
    for (int dt = 0; dt < 2; ++dt)
      va[dt] = *reinterpret_cast<const bf16x8*>(&Vt[wh][((dt << 4) + lo) * 72 + (kt << 5) + (hi << 3)]);
#pragma unroll
    for (int il = 0; il < 2; ++il)
#pragma unroll
      for (int dt = 0; dt < 2; ++dt) oa[il][dt] = mfma16(pa[il], va[dt], oa[il][dt]);
  }

  bf16_t* ob = o + (size_t)win * (64 * 256) + h * 32;
#pragma unroll
  for (int il = 0; il < 2; ++il)
#pragma unroll
    for (int r = 0; r < 4; ++r) {
      int n = (sub << 5) + (il << 4) + (hi << 2) + r;
      float piv = pinv[il][r];
#pragma unroll
      for (int dt = 0; dt < 2; ++dt)
        ob[(size_t)n * 256 + (dt << 4) + lo] = to_bf16(oa[il][dt][r] * piv);
    }
}

// ---------------- launch ----------------
extern "C" void kernel_launch(void* const* d_in, const int* in_sizes, int n_in,
                              void* d_out, int out_size, void* d_ws, size_t ws_size,
                              hipStream_t stream) {
  const float* x      = (const float*)d_in[0];
  const float* n1g    = (const float*)d_in[1];
  const float* n1b    = (const float*)d_in[2];
  const float* qkv_w  = (const float*)d_in[3];
  const float* qkv_b  = (const float*)d_in[4];
  const float* rpbt   = (const float*)d_in[5];
  const float* proj_w = (const float*)d_in[6];
  const float* proj_b = (const float*)d_in[7];
  const float* n2g    = (const float*)d_in[8];
  const float* n2b    = (const float*)d_in[9];
  const float* fc1_w  = (const float*)d_in[10];
  const float* fc1_b  = (const float*)d_in[11];
  const float* fc2_w  = (const float*)d_in[12];
  const float* fc2_b  = (const float*)d_in[13];
  float* out = (float*)d_out;
  char*  ws  = (char*)d_ws;

  // ws: [0,64Mi) hln -> obuf -> h2 chunk | [64Mi,128Mi) qbuf -> x2n | [128Mi..] weights+bias
  // d_out doubles as scratch: k,v bf16 (head-major) until proj, then x2/out fp32.
  const size_t MB64 = 67108864;
  bf16_t* hln  = (bf16_t*)(ws);
  bf16_t* obuf = (bf16_t*)(ws);
  bf16_t* h2   = (bf16_t*)(ws);
  bf16_t* qbuf = (bf16_t*)(ws + MB64);
  bf16_t* x2n  = (bf16_t*)(ws + MB64);
  bf16_t* wb   = (bf16_t*)(ws + 2 * MB64);
  bf16_t* qkv_wb  = wb;                   // 196608 el
  bf16_t* proj_wb = qkv_wb + 196608;      // 65536
  bf16_t* fc1_wb  = proj_wb + 65536;      // 262144
  bf16_t* fc2_wb  = fc1_wb + 262144;      // 262144
  float*  biast   = (float*)(fc2_wb + 262144);  // 131072 f32 = 512KB
  bf16_t* kbuf = (bf16_t*)d_out;          // 33554432 el (64MiB)
  bf16_t* vbuf = kbuf + 33554432;

  const int SMEM_G = 73728;               // 3x(As 8KB + Bs 16KB)
  const int SMEM_P = 78848;               // + LN scratch (EPI2)
  hipFuncSetAttribute(reinterpret_cast<const void*>(gemm128x256<1>),
                      hipFuncAttributeMaxDynamicSharedMemorySize, SMEM_G);
  hipFuncSetAttribute(reinterpret_cast<const void*>(gemm128x256<2>),
                      hipFuncAttributeMaxDynamicSharedMemorySize, SMEM_P);
  hipFuncSetAttribute(reinterpret_cast<const void*>(gemm128x256<4>),
                      hipFuncAttributeMaxDynamicSharedMemorySize, SMEM_G);

  // weights -> bf16 + rpb/mask bias table (one launch)
  prep_kernel<<<3584, 256, 0, stream>>>(qkv_w, proj_w, fc1_w, fc2_w, rpbt,
                                        qkv_wb, proj_wb, fc1_wb, fc2_wb, biast);

  // LN1 + shift + window partition
  ln_kernel<true><<<32768, 256, 0, stream>>>(x, n1g, n1b, hln);

  // fused QKV -> head-major q/k/v (nwg = 1024*3 = 3072, %8==0)
  gemm128x256<4><<<3072, 512, SMEM_G, stream>>>(hln, qkv_wb, qkv_b, qbuf, kbuf, vbuf,
                                                nullptr, nullptr, nullptr, nullptr,
                                                MROWS, 768, 256, 3);

  // windowed attention (4 window-heads per 512-thread block)
  attn_kernel<<<4096, 512, 0, stream>>>(qbuf, kbuf, vbuf, biast, obuf);

  // proj + reverse-scatter + residual -> x2 fp32 in d_out, FUSED LN2 -> x2n (nwg=1024)
  gemm128x256<2><<<1024, 512, SMEM_P, stream>>>(obuf, proj_wb, proj_b, out, nullptr, nullptr,
                                                x, n2g, n2b, x2n, MROWS, 256, 256, 1);

  // MLP in 4 row-chunks (h2 chunk = 32768 x 1024 bf16 = 64MB, L3-resident)
  for (int c = 0; c < 4; ++c) {
    const bf16_t* xa = x2n + (size_t)c * 32768 * 256;
    gemm128x256<1><<<1024, 512, SMEM_G, stream>>>(xa, fc1_wb, fc1_b, h2, nullptr, nullptr,
                                                  nullptr, nullptr, nullptr, nullptr,
                                                  32768, 1024, 256, 4);
    gemm_bt<3><<<512, 256, 0, stream>>>(h2, fc2_wb, fc2_b, out + (size_t)c * 32768 * 256,
                                        32768, 256, 1024, 2);
  }
}

// Round 18
// 582.045 us; speedup vs baseline: 3.1593x; 1.0036x over previous
//
#include <hip/hip_runtime.h>
#include <hip/hip_bf16.h>
#include <stdint.h>

typedef __bf16 bf16_t;
typedef __bf16 bf16x8 __attribute__((ext_vector_type(8)));
typedef __bf16 bf16x4 __attribute__((ext_vector_type(4)));
typedef float f32x4 __attribute__((ext_vector_type(4)));

// Problem constants: B=32, H=W=64, C=256, heads=8, ws=8, ss=4
#define MROWS 131072   // B * 64 * 64 tokens (window layout rows)

__device__ __forceinline__ bf16_t to_bf16(float f) {
  __hip_bfloat16 h = __float2bfloat16(f);   // RNE
  return *reinterpret_cast<bf16_t*>(&h);
}

__device__ __forceinline__ f32x4 mfma16(bf16x8 a, bf16x8 b, f32x4 c) {
  return __builtin_amdgcn_mfma_f32_16x16x32_bf16(a, b, c, 0, 0, 0);
}

__device__ __forceinline__ void gload16(const void* g, void* l) {
  __builtin_amdgcn_global_load_lds(
      (const __attribute__((address_space(1))) void*)g,
      (__attribute__((address_space(3))) void*)l, 16, 0, 0);
}

// window-layout row m  ->  x row (shift+partition gather; reverse+unshift scatter)
__device__ __forceinline__ int map_row(int m) {
  int b   = m >> 12;
  int rem = m & 4095;
  int win = rem >> 6;
  int n   = rem & 63;
  int gh  = ((win >> 3) << 3) + (n >> 3);
  int gw  = ((win & 7) << 3) + (n & 7);
  int sh  = (gh + 4) & 63;
  int sw  = (gw + 4) & 63;
  return (b << 12) + (sh << 6) + sw;
}

// ---------------- prep: fp32->bf16 weight convert + rpb/mask bias table, one launch ----
// blocks [0,3072): weight convert (786432 el). blocks [3072,3584): bias table.
__global__ __launch_bounds__(256) void prep_kernel(const float* __restrict__ qkv_w,
                                                   const float* __restrict__ proj_w,
                                                   const float* __restrict__ fc1_w,
                                                   const float* __restrict__ fc2_w,
                                                   const float* __restrict__ rpbt,
                                                   bf16_t* __restrict__ qkv_o,
                                                   bf16_t* __restrict__ proj_o,
                                                   bf16_t* __restrict__ fc1_o,
                                                   bf16_t* __restrict__ fc2_o,
                                                   float* __restrict__ bias) {
  if (blockIdx.x < 3072) {
    int i = blockIdx.x * 256 + threadIdx.x;   // 0 .. 786431
    if (i < 196608)       qkv_o[i] = to_bf16(qkv_w[i]);
    else if (i < 262144)  proj_o[i - 196608] = to_bf16(proj_w[i - 196608]);
    else if (i < 524288)  fc1_o[i - 262144] = to_bf16(fc1_w[i - 262144]);
    else                  fc2_o[i - 524288] = to_bf16(fc2_w[i - 524288]);
  } else {
    int idx = (blockIdx.x - 3072) * 256 + threadIdx.x;   // 0 .. 131071
    int m = idx & 63, n = (idx >> 6) & 63, h = (idx >> 12) & 7, c = idx >> 15;
    int yn = n >> 3, xn = n & 7, ym = m >> 3, xm = m & 7;
    float v = rpbt[((yn - ym + 7) * 15 + (xn - xm + 7)) * 8 + h];
    int rn = (c & 2) ? (yn < 4 ? 1 : 2) : 0;
    int cn = (c & 1) ? (xn < 4 ? 1 : 2) : 0;
    int rm = (c & 2) ? (ym < 4 ? 1 : 2) : 0;
    int cm = (c & 1) ? (xm < 4 ? 1 : 2) : 0;
    if (rn * 3 + cn != rm * 3 + cm) v -= 100.0f;
    bias[idx] = v;
  }
}

// ---------------- LayerNorm (wave per row), row-permuted gather (LN1) ----------------
template <bool PERM>
__global__ __launch_bounds__(256) void ln_kernel(const float* __restrict__ xin,
                                                 const float* __restrict__ g,
                                                 const float* __restrict__ b,
                                                 bf16_t* __restrict__ out) {
  int row  = (blockIdx.x << 2) + (threadIdx.x >> 6);
  int lane = threadIdx.x & 63;
  int src  = PERM ? map_row(row) : row;
  float4 v = *reinterpret_cast<const float4*>(xin + (size_t)src * 256 + (lane << 2));
  float s = v.x + v.y + v.z + v.w;
#pragma unroll
  for (int d = 1; d < 64; d <<= 1) s += __shfl_xor(s, d);
  float mean = s * 0.00390625f;
  float ax = v.x - mean, ay = v.y - mean, az = v.z - mean, aw = v.w - mean;
  float s2 = ax * ax + ay * ay + az * az + aw * aw;
#pragma unroll
  for (int d = 1; d < 64; d <<= 1) s2 += __shfl_xor(s2, d);
  float rstd = rsqrtf(s2 * 0.00390625f + 1e-5f);
  float4 gv = *reinterpret_cast<const float4*>(g + (lane << 2));
  float4 bv = *reinterpret_cast<const float4*>(b + (lane << 2));
  bf16x4 o4;
  o4[0] = to_bf16(ax * rstd * gv.x + bv.x);
  o4[1] = to_bf16(ay * rstd * gv.y + bv.y);
  o4[2] = to_bf16(az * rstd * gv.z + bv.z);
  o4[3] = to_bf16(aw * rstd * gv.w + bv.w);
  *reinterpret_cast<bf16x4*>(out + (size_t)row * 256 + (lane << 2)) = o4;
}

// ======== 128(M)x256(N)-tile, 8 waves (2Mx4N), BK=32, 3-stage counted vmcnt ========
// Triple-buffered LDS 72KB -> 2 blocks/CU; steady-state s_waitcnt vmcnt(3);
// ONE barrier per K-tile (third buffer makes the extra buf-dead barrier unnecessary).
// T2 swizzle both-sides; T1 XCD swizzle; T5 setprio.
// EPI 1: GELU -> bf16 via LDS-bounce coalesced store (h2)
// EPI 2: proj: fp32 permuted store + resid + FUSED LN2 -> x2n
// EPI 4: qkv head-major split via LDS-bounce: wave w streams head w's 8KB block
template <int EPI>
__global__ __launch_bounds__(512, 4) void gemm128x256(const bf16_t* __restrict__ A,
                                                      const bf16_t* __restrict__ W,
                                                      const float* __restrict__ bias,
                                                      void* __restrict__ outp,
                                                      void* __restrict__ outp2,
                                                      void* __restrict__ outp3,
                                                      const float* __restrict__ resid,
                                                      const float* __restrict__ n2g,
                                                      const float* __restrict__ n2b,
                                                      bf16_t* __restrict__ x2n,
                                                      int M, int N, int K, int NBN) {
  extern __shared__ __align__(16) char smem[];
  bf16_t* As  = (bf16_t*)smem;              // [3][128*32]  (24 KB)
  bf16_t* Bs  = As + 3 * 4096;              // [3][256*32]  (48 KB)
  float*  lnS = (float*)(Bs + 3 * 8192);    // EPI2: [128][4]
  float*  lnQ = lnS + 512;                  // [128][4]
  float*  lnMR = lnQ + 512;                 // [128][2]
  const int tid  = threadIdx.x;
  const int lane = tid & 63, lo = lane & 15, hi = lane >> 4;
  const int wid  = tid >> 6, wm = wid >> 2, wn = wid & 3;
  const int cpx = gridDim.x >> 3;           // T1 XCD chunk swizzle
  const int wg  = (blockIdx.x & 7) * cpx + (blockIdx.x >> 3);
  const int bn = (wg % NBN) << 8, bm = (wg / NBN) << 7;
  f32x4 acc[4][4] = {};

  // STAGE one K-tile: 3 gloads/thread (A:1, B:2); source 16B-slot pre-swizzled (T2)
#define STG(buf, kt)                                                          \
  {                                                                           \
    int k0s = (kt) << 5;                                                      \
    {                                                                         \
      int ch = tid;                                                           \
      int row = ch >> 2, sl = ((ch & 3) ^ ((row >> 1) & 3)) << 3;             \
      gload16(A + (size_t)(bm + row) * K + k0s + sl,                          \
              &As[((buf) << 12) + (ch << 3)]);                                \
    }                                                                         \
    _Pragma("unroll") for (int l = 0; l < 2; ++l) {                           \
      int ch = (l << 9) + tid;                                                \
      int row = ch >> 2, sl = ((ch & 3) ^ ((row >> 1) & 3)) << 3;             \
      gload16(W + (size_t)(bn + row) * K + k0s + sl,                          \
              &Bs[((buf) << 13) + (ch << 3)]);                                \
    }                                                                         \
  }

  const int nt = K >> 5;                    // 8 (K=256)
  STG(0, 0);
  STG(1, 1);                                // 6 loads/thread outstanding

  int cb = 0;
  for (int t = 0; t < nt; ++t) {
    if (t + 1 < nt) { asm volatile("s_waitcnt vmcnt(3)" ::: "memory"); }
    else            { asm volatile("s_waitcnt vmcnt(0)" ::: "memory"); }
    __builtin_amdgcn_s_barrier();           // tile t ready; buf[t-1] reads done
    if (t + 2 < nt) {
      int sb = (cb == 0) ? 2 : cb - 1;      // (cb+2)%3
      STG(sb, t + 2);
    }
    const bf16_t* as = &As[cb << 12];
    const bf16_t* bs = &Bs[cb << 13];
    bf16x8 af[4], bfr[4];
#pragma unroll
    for (int i = 0; i < 4; ++i) {
      int ra = (wm << 6) + (i << 4) + lo;
      af[i] = *reinterpret_cast<const bf16x8*>(&as[ra * 32 + ((hi ^ ((ra >> 1) & 3)) << 3)]);
    }
#pragma unroll
    for (int j = 0; j < 4; ++j) {
      int rb = (wn << 6) + (j << 4) + lo;
      bfr[j] = *reinterpret_cast<const bf16x8*>(&bs[rb * 32 + ((hi ^ ((rb >> 1) & 3)) << 3)]);
    }
    __builtin_amdgcn_s_setprio(1);          // T5
#pragma unroll
    for (int i = 0; i < 4; ++i)
#pragma unroll
      for (int j = 0; j < 4; ++j)
        acc[i][j] = mfma16(af[i], bfr[j], acc[i][j]);
    __builtin_amdgcn_s_setprio(0);
    cb = (cb == 2) ? 0 : cb + 1;
  }
#undef STG

  float bv4[4];
#pragma unroll
  for (int nf = 0; nf < 4; ++nf) bv4[nf] = bias[bn + (wn << 6) + (nf << 4) + lo];

  if constexpr (EPI == 2) {
    // proj epilogue (BN = N = 256: full rows in-block): x2 = resid + o + b -> out
    // (permuted rows, fp32), then fused LN2 -> x2n bf16.
    float* o = (float*)outp;
    float gv[4], bnv[4];
#pragma unroll
    for (int nf = 0; nf < 4; ++nf) {
      int col = (wn << 6) + (nf << 4) + lo;
      gv[nf] = n2g[col]; bnv[nf] = n2b[col];
    }
#pragma unroll
    for (int mf = 0; mf < 4; ++mf)
#pragma unroll
      for (int r = 0; r < 4; ++r) {
        int rl = (wm << 6) + (mf << 4) + (hi << 2) + r;   // 0..127
        int xr = map_row(bm + rl);
        float s = 0.f, q = 0.f;
#pragma unroll
        for (int nf = 0; nf < 4; ++nf) {
          int col = (wn << 6) + (nf << 4) + lo;
          size_t idx = (size_t)xr * 256 + col;
          float v = resid[idx] + acc[mf][nf][r] + bv4[nf];
          acc[mf][nf][r] = v;
          o[idx] = v;
          s += v; q += v * v;
        }
#pragma unroll
        for (int d = 1; d < 16; d <<= 1) { s += __shfl_xor(s, d); q += __shfl_xor(q, d); }
        if (lo == 0) { lnS[(rl << 2) + wn] = s; lnQ[(rl << 2) + wn] = q; }
      }
    __syncthreads();
    if (tid < 128) {
      float s = lnS[tid << 2] + lnS[(tid << 2) + 1] + lnS[(tid << 2) + 2] + lnS[(tid << 2) + 3];
      float q = lnQ[tid << 2] + lnQ[(tid << 2) + 1] + lnQ[(tid << 2) + 2] + lnQ[(tid << 2) + 3];
      float mean = s * 0.00390625f;
      float var  = q * 0.00390625f - mean * mean;
      lnMR[tid << 1] = mean;
      lnMR[(tid << 1) + 1] = rsqrtf(var + 1e-5f);
    }
    __syncthreads();
#pragma unroll
    for (int mf = 0; mf < 4; ++mf)
#pragma unroll
      for (int r = 0; r < 4; ++r) {
        int rl = (wm << 6) + (mf << 4) + (hi << 2) + r;
        int xr = map_row(bm + rl);
        float mean = lnMR[rl << 1], rstd = lnMR[(rl << 1) + 1];
#pragma unroll
        for (int nf = 0; nf < 4; ++nf) {
          int col = (wn << 6) + (nf << 4) + lo;
          x2n[(size_t)xr * 256 + col] = to_bf16((acc[mf][nf][r] - mean) * rstd * gv[nf] + bnv[nf]);
        }
      }
  } else if constexpr (EPI == 4) {
    // QKV epilogue: LDS-bounce -> wave w streams head w's contiguous 8KB block.
    __syncthreads();                        // all waves done with As/Bs
    bf16_t* Os = (bf16_t*)smem;             // [128][264] bf16 (67.6 KB <= 72 KB)
#pragma unroll
    for (int mf = 0; mf < 4; ++mf)
#pragma unroll
      for (int r = 0; r < 4; ++r) {
        int rl = (wm << 6) + (mf << 4) + (hi << 2) + r;
#pragma unroll
        for (int nf = 0; nf < 4; ++nf) {
          int col = (wn << 6) + (nf << 4) + lo;
          Os[rl * 264 + col] = to_bf16(acc[mf][nf][r] + bv4[nf]);
        }
      }
    __syncthreads();
    {
      bf16_t* base = (bn == 0) ? (bf16_t*)outp
                   : (bn == 256) ? (bf16_t*)outp2 : (bf16_t*)outp3;
      bf16_t* dst = base + ((size_t)wid * MROWS + bm) * 32;   // head = wid
#pragma unroll
      for (int p = 0; p < 8; ++p) {
        int off = (p << 9) + (lane << 3);   // elem offset in 8KB head block
        int row = off >> 5, d0 = off & 31;  // row = p*16 + lane/4, d0 = (lane&3)*8
        bf16x8 v = *reinterpret_cast<const bf16x8*>(&Os[row * 264 + (wid << 5) + d0]);
        *reinterpret_cast<bf16x8*>(dst + off) = v;
      }
    }
  } else {
    // EPI 1: GELU -> bf16 via LDS-bounce, coalesced row-major store (h2)
    __syncthreads();                        // all waves done with As/Bs
    bf16_t* Os = (bf16_t*)smem;             // [128][264]
#pragma unroll
    for (int mf = 0; mf < 4; ++mf)
#pragma unroll
      for (int r = 0; r < 4; ++r) {
        int rl = (wm << 6) + (mf << 4) + (hi << 2) + r;
#pragma unroll
        for (int nf = 0; nf < 4; ++nf) {
          int col = (wn << 6) + (nf << 4) + lo;
          float v = acc[mf][nf][r] + bv4[nf];
          if constexpr (EPI == 1) v = 0.5f * v * (1.0f + erff(v * 0.70710678118654752f));
          Os[rl * 264 + col] = to_bf16(v);
        }
      }
    __syncthreads();
    {
      bf16_t* o = (bf16_t*)outp;
#pragma unroll
      for (int p = 0; p < 8; ++p) {
        int off = (p << 9) + (lane << 3);   // within wave's 16-row x 256-col slab
        int row = (wid << 4) + (off >> 8);  // wave w -> rows w*16..+16
        int col = off & 255;
        bf16x8 v = *reinterpret_cast<const bf16x8*>(&Os[row * 264 + col]);
        *reinterpret_cast<bf16x8*>(o + (size_t)(bm + row) * N + bn + col) = v;
      }
    }
  }
}

// ---------------- 128x128 bf16 GEMM, 3-stage counted-vmcnt (r8 proven) — FC2 ------
template <int EPI>
__global__ __launch_bounds__(256) void gemm_bt(const bf16_t* __restrict__ A,
                                               const bf16_t* __restrict__ W,
                                               const float* __restrict__ bias,
                                               void* __restrict__ outp,
                                               int M, int N, int K, int NBN) {
  __shared__ __align__(16) bf16_t As[3 * 128 * 32];
  __shared__ __align__(16) bf16_t Bs[3 * 128 * 32];
  const int tid  = threadIdx.x;
  const int lane = tid & 63, lo = lane & 15, hi = lane >> 4;
  const int wave = tid >> 6;
  const int cpx = gridDim.x >> 3;
  const int wg  = (blockIdx.x & 7) * cpx + (blockIdx.x >> 3);
  const int bn = (wg % NBN) << 7, bm = (wg / NBN) << 7;
  const int wr = (wave >> 1) << 6, wc = (wave & 1) << 6;
  f32x4 acc[4][4] = {};

#define STAGE(buf, kt)                                                         \
  {                                                                            \
    int k0s = (kt) << 5;                                                       \
    _Pragma("unroll") for (int it = 0; it < 2; ++it) {                         \
      int ch = (it << 8) + tid;                                                \
      int r = ch >> 2;                                                         \
      int kf = ((ch & 3) ^ ((r >> 1) & 3)) << 3;                               \
      gload16(A + (size_t)(bm + r) * K + k0s + kf, &As[((buf) << 12) + (ch << 3)]); \
      gload16(W + (size_t)(bn + r) * K + k0s + kf, &Bs[((buf) << 12) + (ch << 3)]); \
    }                                                                          \
  }

  const int nt = K >> 5;
  STAGE(0, 0);
  STAGE(1, 1);

  int cb = 0;
  for (int t = 0; t < nt; ++t) {
    if (t + 1 < nt) { asm volatile("s_waitcnt vmcnt(4)" ::: "memory"); }
    else            { asm volatile("s_waitcnt vmcnt(0)" ::: "memory"); }
    __builtin_amdgcn_s_barrier();
    if (t + 2 < nt) {
      int sb = (cb == 0) ? 2 : cb - 1;
      STAGE(sb, t + 2);
    }
    const bf16_t* as = &As[cb << 12];
    const bf16_t* bs = &Bs[cb << 12];
    bf16x8 af[4], bfr[4];
#pragma unroll
    for (int i = 0; i < 4; ++i) {
      int ra = wr + (i << 4) + lo;
      af[i] = *reinterpret_cast<const bf16x8*>(&as[ra * 32 + ((hi ^ ((ra >> 1) & 3)) << 3)]);
    }
#pragma unroll
    for (int j = 0; j < 4; ++j) {
      int rb = wc + (j << 4) + lo;
      bfr[j] = *reinterpret_cast<const bf16x8*>(&bs[rb * 32 + ((hi ^ ((rb >> 1) & 3)) << 3)]);
    }
    __builtin_amdgcn_s_setprio(1);
#pragma unroll
    for (int i = 0; i < 4; ++i)
#pragma unroll
      for (int j = 0; j < 4; ++j)
        acc[i][j] = mfma16(af[i], bfr[j], acc[i][j]);
    __builtin_amdgcn_s_setprio(0);
    cb = (cb == 2) ? 0 : cb + 1;
  }
#undef STAGE

  float bv[4];
#pragma unroll
  for (int j = 0; j < 4; ++j) bv[j] = bias[bn + wc + (j << 4) + lo];

#pragma unroll
  for (int i = 0; i < 4; ++i)
#pragma unroll
    for (int r = 0; r < 4; ++r) {
      int row = bm + wr + (i << 4) + (hi << 2) + r;
      float* o = (float*)outp;   // EPI 3 only
#pragma unroll
      for (int j = 0; j < 4; ++j) {
        int col = bn + wc + (j << 4) + lo;
        size_t idx = (size_t)row * 256 + col;
        o[idx] = o[idx] + acc[i][j][r] + bv[j];
      }
    }
}

// ---------------- windowed attention v2: wave PAIR per (window, head) ----------------
// 512 threads = 8 waves = 4 window-heads; pair (wh, sub) splits S/P/O rows by half.
// T5: setprio around both MFMA clusters (waves are loosely coupled -> scheduler
// can favor the MFMA-issuing wave; catalog m191: +4-7% on attn).
__global__ __launch_bounds__(512) void attn_kernel(const bf16_t* __restrict__ qh,
                                                   const bf16_t* __restrict__ kh,
                                                   const bf16_t* __restrict__ vh,
                                                   const float* __restrict__ bias,
                                                   bf16_t* __restrict__ o) {
  __shared__ __align__(16) bf16_t Pl[4][64 * 72];
  __shared__ __align__(16) bf16_t Vt[4][32 * 72];
  const int tid = threadIdx.x;
  const int lane = tid & 63, lo = lane & 15, hi = lane >> 4;
  const int w = tid >> 6;                   // 0..7
  const int wh = w >> 1, sub = w & 1;       // window-head slot, row-half
  const int id = (blockIdx.x << 2) + wh;    // 0..16383
  const int win = id >> 3, h = id & 7;
  const size_t hb = ((size_t)h * MROWS + (size_t)win * 64) * 32;
  const bf16_t* qb = qh + hb;
  const bf16_t* kb = kh + hb;
  const bf16_t* vb = vh + hb;

  // stage V transposed: wave covers tokens m = sub*32 .. +31, both d-halves
  {
    int m  = (sub << 5) + (lane & 31);
    int dh = (lane >> 5) << 4;              // 0 | 16
    const bf16_t* vp = vb + (size_t)m * 32 + dh;
    bf16x8 v0 = *reinterpret_cast<const bf16x8*>(vp);
    bf16x8 v1 = *reinterpret_cast<const bf16x8*>(vp + 8);
#pragma unroll
    for (int e = 0; e < 8; ++e) {
      Vt[wh][(dh + e) * 72 + m]     = v0[e];
      Vt[wh][(dh + 8 + e) * 72 + m] = v1[e];
    }
  }

  // QK^T: rows n = sub*32 .. +31 (2 frags), all 64 K rows (4 frags)
  bf16x8 qa[2], ka[4];
#pragma unroll
  for (int il = 0; il < 2; ++il)
    qa[il] = *reinterpret_cast<const bf16x8*>(qb + ((sub << 5) + (il << 4) + lo) * 32 + (hi << 3));
#pragma unroll
  for (int j = 0; j < 4; ++j)
    ka[j] = *reinterpret_cast<const bf16x8*>(kb + ((j << 4) + lo) * 32 + (hi << 3));
  f32x4 s4[2][4] = {};
  __builtin_amdgcn_s_setprio(1);            // T5
#pragma unroll
  for (int il = 0; il < 2; ++il)
#pragma unroll
    for (int j = 0; j < 4; ++j) s4[il][j] = mfma16(qa[il], ka[j], s4[il][j]);
  __builtin_amdgcn_s_setprio(0);

  const int whw = (win & 63) >> 3, www = win & 7;
  const int cls = ((whw == 7) ? 2 : 0) + ((www == 7) ? 1 : 0);
  const float* bb = bias + ((size_t)cls * 8 + h) * 4096;
  const float scale = 0.17677669529663687f;  // 1/sqrt(32)

  float pinv[2][4];
#pragma unroll
  for (int il = 0; il < 2; ++il) {
#pragma unroll
    for (int r = 0; r < 4; ++r) {
      int n = (sub << 5) + (il << 4) + (hi << 2) + r;
      const float* brow = bb + n * 64 + lo;
      float vals[4], mx = -1e30f;
#pragma unroll
      for (int j = 0; j < 4; ++j) {
        float val = s4[il][j][r] * scale + brow[j << 4];
        vals[j] = val;
        mx = fmaxf(mx, val);
      }
#pragma unroll
      for (int d = 1; d < 16; d <<= 1) mx = fmaxf(mx, __shfl_xor(mx, d));
      float sum = 0.0f;
#pragma unroll
      for (int j = 0; j < 4; ++j) {
        float p = __expf(vals[j] - mx);
        sum += p;
        Pl[wh][n * 72 + (j << 4) + lo] = to_bf16(p);
      }
#pragma unroll
      for (int d = 1; d < 16; d <<= 1) sum += __shfl_xor(sum, d);
      pinv[il][r] = 1.0f / sum;
    }
  }

  __syncthreads();   // Vt + Pl complete (pair + block)

  // PV: O[own 32, 32] = P[own 32, 64] @ V[64, 32]
  f32x4 oa[2][2] = {};
#pragma unroll
  for (int kt = 0; kt < 2; ++kt) {
    bf16x8 pa[2], va[2];
#pragma unroll
    for (int il = 0; il < 2; ++il)
      pa[il] = *reinterpret_cast<const bf16x8*>(&Pl[wh][((sub << 5) + (il << 4) + lo) * 72 + (kt << 5) + (hi << 3)]);
#pragma unroll
    for (int dt = 0; dt < 2; ++dt)
      va[dt] = *reinterpret_cast<const bf16x8*>(&Vt[wh][((dt << 4) + lo) * 72 + (kt << 5) + (hi << 3)]);
    __builtin_amdgcn_s_setprio(1);          // T5
#pragma unroll
    for (int il = 0; il < 2; ++il)
#pragma unroll
      for (int dt = 0; dt < 2; ++dt) oa[il][dt] = mfma16(pa[il], va[dt], oa[il][dt]);
    __builtin_amdgcn_s_setprio(0);
  }

  bf16_t* ob = o + (size_t)win * (64 * 256) + h * 32;
#pragma unroll
  for (int il = 0; il < 2; ++il)
#pragma unroll
    for (int r = 0; r < 4; ++r) {
      int n = (sub << 5) + (il << 4) + (hi << 2) + r;
      float piv = pinv[il][r];
#pragma unroll
      for (int dt = 0; dt < 2; ++dt)
        ob[(size_t)n * 256 + (dt << 4) + lo] = to_bf16(oa[il][dt][r] * piv);
    }
}

// ---------------- launch ----------------
extern "C" void kernel_launch(void* const* d_in, const int* in_sizes, int n_in,
                              void* d_out, int out_size, void* d_ws, size_t ws_size,
                              hipStream_t stream) {
  const float* x      = (const float*)d_in[0];
  const float* n1g    = (const float*)d_in[1];
  const float* n1b    = (const float*)d_in[2];
  const float* qkv_w  = (const float*)d_in[3];
  const float* qkv_b  = (const float*)d_in[4];
  const float* rpbt   = (const float*)d_in[5];
  const float* proj_w = (const float*)d_in[6];
  const float* proj_b = (const float*)d_in[7];
  const float* n2g    = (const float*)d_in[8];
  const float* n2b    = (const float*)d_in[9];
  const float* fc1_w  = (const float*)d_in[10];
  const float* fc1_b  = (const float*)d_in[11];
  const float* fc2_w  = (const float*)d_in[12];
  const float* fc2_b  = (const float*)d_in[13];
  float* out = (float*)d_out;
  char*  ws  = (char*)d_ws;

  // ws: [0,64Mi) hln -> obuf -> h2 chunk | [64Mi,128Mi) qbuf -> x2n | [128Mi..] weights+bias
  // d_out doubles as scratch: k,v bf16 (head-major) until proj, then x2/out fp32.
  const size_t MB64 = 67108864;
  bf16_t* hln  = (bf16_t*)(ws);
  bf16_t* obuf = (bf16_t*)(ws);
  bf16_t* h2   = (bf16_t*)(ws);
  bf16_t* qbuf = (bf16_t*)(ws + MB64);
  bf16_t* x2n  = (bf16_t*)(ws + MB64);
  bf16_t* wb   = (bf16_t*)(ws + 2 * MB64);
  bf16_t* qkv_wb  = wb;                   // 196608 el
  bf16_t* proj_wb = qkv_wb + 196608;      // 65536
  bf16_t* fc1_wb  = proj_wb + 65536;      // 262144
  bf16_t* fc2_wb  = fc1_wb + 262144;      // 262144
  float*  biast   = (float*)(fc2_wb + 262144);  // 131072 f32 = 512KB
  bf16_t* kbuf = (bf16_t*)d_out;          // 33554432 el (64MiB)
  bf16_t* vbuf = kbuf + 33554432;

  const int SMEM_G = 73728;               // 3x(As 8KB + Bs 16KB)
  const int SMEM_P = 78848;               // + LN scratch (EPI2)
  hipFuncSetAttribute(reinterpret_cast<const void*>(gemm128x256<1>),
                      hipFuncAttributeMaxDynamicSharedMemorySize, SMEM_G);
  hipFuncSetAttribute(reinterpret_cast<const void*>(gemm128x256<2>),
                      hipFuncAttributeMaxDynamicSharedMemorySize, SMEM_P);
  hipFuncSetAttribute(reinterpret_cast<const void*>(gemm128x256<4>),
                      hipFuncAttributeMaxDynamicSharedMemorySize, SMEM_G);

  // weights -> bf16 + rpb/mask bias table (one launch)
  prep_kernel<<<3584, 256, 0, stream>>>(qkv_w, proj_w, fc1_w, fc2_w, rpbt,
                                        qkv_wb, proj_wb, fc1_wb, fc2_wb, biast);

  // LN1 + shift + window partition
  ln_kernel<true><<<32768, 256, 0, stream>>>(x, n1g, n1b, hln);

  // fused QKV -> head-major q/k/v (nwg = 1024*3 = 3072, %8==0)
  gemm128x256<4><<<3072, 512, SMEM_G, stream>>>(hln, qkv_wb, qkv_b, qbuf, kbuf, vbuf,
                                                nullptr, nullptr, nullptr, nullptr,
                                                MROWS, 768, 256, 3);

  // windowed attention (4 window-heads per 512-thread block)
  attn_kernel<<<4096, 512, 0, stream>>>(qbuf, kbuf, vbuf, biast, obuf);

  // proj + reverse-scatter + residual -> x2 fp32 in d_out, FUSED LN2 -> x2n (nwg=1024)
  gemm128x256<2><<<1024, 512, SMEM_P, stream>>>(obuf, proj_wb, proj_b, out, nullptr, nullptr,
                                                x, n2g, n2b, x2n, MROWS, 256, 256, 1);

  // MLP in 4 row-chunks (h2 chunk = 32768 x 1024 bf16 = 64MB, L3-resident)
  for (int c = 0; c < 4; ++c) {
    const bf16_t* xa = x2n + (size_t)c * 32768 * 256;
    gemm128x256<1><<<1024, 512, SMEM_G, stream>>>(xa, fc1_wb, fc1_b, h2, nullptr, nullptr,
                                                  nullptr, nullptr, nullptr, nullptr,
                                                  32768, 1024, 256, 4);
    gemm_bt<3><<<512, 256, 0, stream>>>(h2, fc2_wb, fc2_b, out + (size_t)c * 32768 * 256,
                                        32768, 256, 1024, 2);
  }
}